// Round 1
// baseline (1157.577 us; speedup 1.0000x reference)
//
#include <hip/hip_runtime.h>

// EventWarping: contrast-maximization loss for event-camera flow.
// Reference shapes: flow [B,2,H,W] f32, ts [B,N,1] f32, ys/xs/pol [B,N] i32.
// Output: single f32 scalar = fw_loss + bw_loss + 0.001 * smoothness.

constexpr int H = 480;
constexpr int W = 640;
constexpr int HW = H * W;
constexpr int B = 8;
constexpr int N = 131072;
constexpr float FLOW_SCALING = 640.0f;   // max(H, W)
constexpr float EPS = 1e-9f;

// Workspace layout:
//   doubles acc[64] at offset 0 (512 bytes):
//     acc[0..15]  : l sum per job j (j = b*2 + t; t=0 fw, t=1 bw)
//     acc[16..31] : nz count per job j
//     acc[32..35] : smoothness sums dx, dy, dr, ur
//   float images at offset 512: per resident job slot, 4 images of HW floats:
//     [w_pos, w_neg, wts_pos, wts_neg]
constexpr size_t ACC_BYTES = 512;
constexpr size_t IMG_FLOATS_PER_JOB = (size_t)4 * HW;
constexpr size_t IMG_BYTES_PER_JOB = IMG_FLOATS_PER_JOB * sizeof(float);

__device__ inline double blk_reduce(double v, double* sm) {
    __syncthreads();  // protect sm reuse across consecutive calls
    #pragma unroll
    for (int o = 32; o > 0; o >>= 1) v += __shfl_down(v, o, 64);
    int lane = threadIdx.x & 63;
    int wid  = threadIdx.x >> 6;
    if (lane == 0) sm[wid] = v;
    __syncthreads();
    double r = 0.0;
    if (threadIdx.x == 0) {
        int nw = (int)(blockDim.x >> 6);
        for (int w2 = 0; w2 < nw; ++w2) r += sm[w2];
    }
    return r;  // valid on thread 0 only
}

// One thread per (job, event). 8 fp32 atomics per thread (4 corners x 2 vals).
__global__ void splat_kernel(const float* __restrict__ flow,
                             const float* __restrict__ ts,
                             const int* __restrict__ ys,
                             const int* __restrict__ xs,
                             const int* __restrict__ pol,
                             float* __restrict__ img, int j0) {
    int n = blockIdx.x * blockDim.x + threadIdx.x;
    if (n >= N) return;
    int slot = blockIdx.y;
    int j = j0 + slot;
    int b = j >> 1;
    int t = j & 1;

    int e = b * N + n;
    int y = ys[e];
    int x = xs[e];
    int p = pol[e];
    float t0 = ts[e];

    int flat = y * W + x;
    float fx = flow[(size_t)(b * 2 + 0) * HW + flat];
    float fy = flow[(size_t)(b * 2 + 1) * HW + flat];

    float tref = (t == 0) ? 1.0f : 0.0f;
    float ts_w = (t == 0) ? t0 : (1.0f - t0);
    float dt = tref - t0;
    float wy = (float)y + dt * fy * FLOW_SCALING;
    float wx = (float)x + dt * fx * FLOW_SCALING;

    float ty = floorf(wy), by = ty + 1.0f;
    float lx = floorf(wx), rx = lx + 1.0f;

    float* wimg = img + (size_t)slot * IMG_FLOATS_PER_JOB + (size_t)(p ? 0 : 1) * HW;
    float* simg = img + (size_t)slot * IMG_FLOATS_PER_JOB + (size_t)(p ? 2 : 3) * HW;

    float cy[2] = {ty, by};
    float cx[2] = {lx, rx};
    #pragma unroll
    for (int a = 0; a < 2; ++a) {
        #pragma unroll
        for (int c = 0; c < 2; ++c) {
            float iy = cy[a], ix = cx[c];
            // Out-of-bounds: reference forces w=0 (added at pixel 0) -> skip is identical.
            if (!(iy >= 0.0f && iy < (float)H && ix >= 0.0f && ix < (float)W)) continue;
            float wgt = fmaxf(0.0f, 1.0f - fabsf(wy - iy)) *
                        fmaxf(0.0f, 1.0f - fabsf(wx - ix));
            int idx = (int)iy * W + (int)ix;
            atomicAdd(&wimg[idx], wgt);
            atomicAdd(&simg[idx], wgt * ts_w);
        }
    }
}

// Per (job slot): l = sum (wts_p/(w_p+eps))^2 + (wts_n/(w_n+eps))^2 ; nz = #(w_p+w_n > 0)
__global__ void reduce_kernel(const float* __restrict__ img,
                              double* __restrict__ acc, int j0) {
    __shared__ double sm[8];
    int slot = blockIdx.y;
    int j = j0 + slot;
    const float* base = img + (size_t)slot * IMG_FLOATS_PER_JOB;

    double l = 0.0, nz = 0.0;
    for (int i = blockIdx.x * blockDim.x + threadIdx.x; i < HW;
         i += gridDim.x * blockDim.x) {
        float wp = base[i];
        float wn = base[HW + i];
        float sp = base[2 * HW + i];
        float sn = base[3 * HW + i];
        float a = sp / (wp + EPS);
        float c = sn / (wn + EPS);
        l += (double)(a * a) + (double)(c * c);
        if (wp + wn > 0.0f) nz += 1.0;
    }
    double lt = blk_reduce(l, sm);
    double nt = blk_reduce(nz, sm);
    if (threadIdx.x == 0) {
        atomicAdd(&acc[j], lt);
        atomicAdd(&acc[16 + j], nt);
    }
}

__device__ inline float charb(float a, float b) {
    return sqrtf(a * a + b * b + 1e-6f);
}

__global__ void smooth_kernel(const float* __restrict__ flow,
                              double* __restrict__ acc) {
    __shared__ double sm[8];
    double sdx = 0.0, sdy = 0.0, sdr = 0.0, sur = 0.0;
    int stride = gridDim.x * blockDim.x;
    for (int i = blockIdx.x * blockDim.x + threadIdx.x; i < B * HW; i += stride) {
        int b = i / HW;
        int rem = i - b * HW;
        int y = rem / W;
        int x = rem - y * W;
        const float* fx = flow + (size_t)(b * 2 + 0) * HW;
        const float* fy = flow + (size_t)(b * 2 + 1) * HW;
        float f00 = fx[rem], g00 = fy[rem];
        bool xe = (x + 1) < W;
        bool ye = (y + 1) < H;
        if (xe) {
            float f01 = fx[rem + 1], g01 = fy[rem + 1];
            sdx += (double)charb(f00 - f01, g00 - g01);
            if (ye) {
                float f10 = fx[rem + W], g10 = fy[rem + W];
                float f11 = fx[rem + W + 1], g11 = fy[rem + W + 1];
                sdy += (double)charb(f00 - f10, g00 - g10);
                sdr += (double)charb(f00 - f11, g00 - g11);
                sur += (double)charb(f10 - f01, g10 - g01);
            }
        } else if (ye) {
            float f10 = fx[rem + W], g10 = fy[rem + W];
            sdy += (double)charb(f00 - f10, g00 - g10);
        }
    }
    double t;
    t = blk_reduce(sdx, sm); if (threadIdx.x == 0) atomicAdd(&acc[32], t);
    t = blk_reduce(sdy, sm); if (threadIdx.x == 0) atomicAdd(&acc[33], t);
    t = blk_reduce(sdr, sm); if (threadIdx.x == 0) atomicAdd(&acc[34], t);
    t = blk_reduce(sur, sm); if (threadIdx.x == 0) atomicAdd(&acc[35], t);
}

__global__ void final_kernel(const double* __restrict__ acc,
                             float* __restrict__ out) {
    double loss = 0.0;
    for (int j = 0; j < 16; ++j) loss += acc[j] / acc[16 + j];
    double ndx = (double)B * H * (W - 1);
    double ndy = (double)B * (H - 1) * W;
    double ndd = (double)B * (H - 1) * (W - 1);
    double smooth =
        (acc[32] / ndx + acc[33] / ndy + acc[34] / ndd + acc[35] / ndd) * 0.25;
    out[0] = (float)(loss + 0.001 * smooth);
}

extern "C" void kernel_launch(void* const* d_in, const int* in_sizes, int n_in,
                              void* d_out, int out_size, void* d_ws, size_t ws_size,
                              hipStream_t stream) {
    const float* flow = (const float*)d_in[0];
    const float* ts   = (const float*)d_in[1];
    const int*   ys   = (const int*)d_in[2];
    const int*   xs   = (const int*)d_in[3];
    const int*   pol  = (const int*)d_in[4];
    float* out = (float*)d_out;

    double* acc = (double*)d_ws;
    float* img = (float*)((char*)d_ws + ACC_BYTES);

    int slots = 1;
    if (ws_size > ACC_BYTES) {
        size_t avail = ws_size - ACC_BYTES;
        size_t s = avail / IMG_BYTES_PER_JOB;
        slots = (int)(s > 16 ? 16 : (s < 1 ? 1 : s));
    }

    hipMemsetAsync(acc, 0, ACC_BYTES, stream);
    smooth_kernel<<<4800, 256, 0, stream>>>(flow, acc);

    for (int j0 = 0; j0 < 16; j0 += slots) {
        int cnt = (16 - j0) < slots ? (16 - j0) : slots;
        hipMemsetAsync(img, 0, (size_t)cnt * IMG_BYTES_PER_JOB, stream);
        dim3 gs((N + 255) / 256, cnt);
        splat_kernel<<<gs, 256, 0, stream>>>(flow, ts, ys, xs, pol, img, j0);
        dim3 gr(300, cnt);
        reduce_kernel<<<gr, 256, 0, stream>>>(img, acc, j0);
    }

    final_kernel<<<1, 1, 0, stream>>>(acc, out);
}

// Round 2
// 734.629 us; speedup vs baseline: 1.5757x; 1.5757x over previous
//
#include <hip/hip_runtime.h>

// EventWarping: contrast-maximization loss for event-camera flow.
// flow [B,2,H,W] f32, ts [B,N,1] f32, ys/xs/pol [B,N] i32 -> scalar f32.
//
// Round 2: splat uses ONE native u64 atomicAdd per corner, fixed-point
// packing w (hi32) and w*ts (lo32) at scale 2^22. Per-pixel weight sums
// are O(10) (random events), so fields never overflow into each other.
// pos/neg entries interleaved per pixel for cache-line locality; fw+bw
// fused into one thread so event/flow loads are amortized.

constexpr int H = 480;
constexpr int W = 640;
constexpr int HW = H * W;
constexpr int B = 8;
constexpr int N = 131072;           // 2^17
constexpr float FLOW_SCALING = 640.0f;
constexpr float EPS = 1e-9f;
constexpr float FP_S = 4194304.0f;  // 2^22
constexpr float FP_INV = 1.0f / 4194304.0f;

// Workspace:
//   doubles acc[64] @0: [0..15] l per job (j=b*2+t), [16..31] nz per job,
//                       [32..35] smooth sums dx,dy,dr,ur
//   u64 images @512: per batch-slot, 2 jobs x HW pixels x {pos,neg} u64
constexpr size_t ACC_BYTES = 512;
constexpr size_t IMG_U64_PER_JOB = (size_t)2 * HW;              // pos,neg per pixel
constexpr size_t IMG_BYTES_PER_JOB = IMG_U64_PER_JOB * 8;       // 4.9 MB
constexpr size_t IMG_BYTES_PER_BATCH = 2 * IMG_BYTES_PER_JOB;   // fw+bw

__device__ inline double blk_reduce(double v, double* sm) {
    __syncthreads();
    #pragma unroll
    for (int o = 32; o > 0; o >>= 1) v += __shfl_down(v, o, 64);
    int lane = threadIdx.x & 63;
    int wid  = threadIdx.x >> 6;
    if (lane == 0) sm[wid] = v;
    __syncthreads();
    double r = 0.0;
    if (threadIdx.x == 0) {
        int nw = (int)(blockDim.x >> 6);
        for (int w2 = 0; w2 < nw; ++w2) r += sm[w2];
    }
    return r;  // thread 0 only
}

__device__ inline unsigned long long pack_ws(float w, float s) {
    unsigned hi = __float2uint_rn(w * FP_S);
    unsigned lo = __float2uint_rn(s * FP_S);
    return ((unsigned long long)hi << 32) | (unsigned long long)lo;
}

// One thread per event; handles both trefs (fw, bw). 8 u64 atomics/thread.
__global__ void splat_kernel(const float* __restrict__ flow,
                             const float* __restrict__ ts,
                             const int* __restrict__ ys,
                             const int* __restrict__ xs,
                             const int* __restrict__ pol,
                             unsigned long long* __restrict__ img, int b0) {
    int n = blockIdx.x * blockDim.x + threadIdx.x;
    if (n >= N) return;
    int bslot = blockIdx.y;
    int b = b0 + bslot;
    int e = b * N + n;

    int y = ys[e];
    int x = xs[e];
    int p = pol[e];
    float t0 = ts[e];

    int flat = y * W + x;
    const float* fb = flow + (size_t)b * 2 * HW;
    float fx = fb[flat];
    float fy = fb[HW + flat];

    int pofs = (p != 0) ? 0 : 1;  // pos events -> entry 0, neg -> entry 1

    #pragma unroll
    for (int t = 0; t < 2; ++t) {
        float tref = (t == 0) ? 1.0f : 0.0f;
        float sw   = (t == 0) ? t0 : (1.0f - t0);
        float dt = tref - t0;
        float wy = (float)y + dt * fy * FLOW_SCALING;
        float wx = (float)x + dt * fx * FLOW_SCALING;
        float ty = floorf(wy), by = ty + 1.0f;
        float lx = floorf(wx), rx = lx + 1.0f;

        unsigned long long* base =
            img + ((size_t)bslot * 2 + t) * IMG_U64_PER_JOB + pofs;

        float cy[2] = {ty, by};
        float cx[2] = {lx, rx};
        #pragma unroll
        for (int a = 0; a < 2; ++a) {
            #pragma unroll
            for (int c = 0; c < 2; ++c) {
                float iy = cy[a], ix = cx[c];
                if (!(iy >= 0.0f && iy < (float)H && ix >= 0.0f && ix < (float)W))
                    continue;  // reference zeroes these weights -> identical
                float wgt = fmaxf(0.0f, 1.0f - fabsf(wy - iy)) *
                            fmaxf(0.0f, 1.0f - fabsf(wx - ix));
                int idx = (int)iy * W + (int)ix;
                atomicAdd(&base[(size_t)idx * 2], pack_ws(wgt, wgt * sw));
            }
        }
    }
}

// Per job slot: l = sum (s_p/(w_p+eps))^2 + (s_n/(w_n+eps))^2 ; nz = #(w_p+w_n>0)
__global__ void reduce_kernel(const unsigned long long* __restrict__ img,
                              double* __restrict__ acc, int j0) {
    __shared__ double sm[8];
    int slot = blockIdx.y;
    int j = j0 + slot;
    const unsigned long long* base = img + (size_t)slot * IMG_U64_PER_JOB;

    double l = 0.0, nz = 0.0;
    for (int i = blockIdx.x * blockDim.x + threadIdx.x; i < HW;
         i += gridDim.x * blockDim.x) {
        unsigned long long vp = base[(size_t)i * 2];
        unsigned long long vn = base[(size_t)i * 2 + 1];
        float wp = (float)(unsigned)(vp >> 32) * FP_INV;
        float sp = (float)(unsigned)(vp & 0xffffffffu) * FP_INV;
        float wn = (float)(unsigned)(vn >> 32) * FP_INV;
        float sn = (float)(unsigned)(vn & 0xffffffffu) * FP_INV;
        float a = sp / (wp + EPS);
        float c = sn / (wn + EPS);
        l += (double)(a * a) + (double)(c * c);
        if (((vp | vn) >> 32) != 0ull) nz += 1.0;
    }
    double lt = blk_reduce(l, sm);
    double nt = blk_reduce(nz, sm);
    if (threadIdx.x == 0) {
        atomicAdd(&acc[j], lt);
        atomicAdd(&acc[16 + j], nt);
    }
}

__device__ inline float charb(float a, float b) {
    return sqrtf(a * a + b * b + 1e-6f);
}

__global__ void smooth_kernel(const float* __restrict__ flow,
                              double* __restrict__ acc) {
    __shared__ double sm[8];
    double sdx = 0.0, sdy = 0.0, sdr = 0.0, sur = 0.0;
    int stride = gridDim.x * blockDim.x;
    for (int i = blockIdx.x * blockDim.x + threadIdx.x; i < B * HW; i += stride) {
        int b = i / HW;
        int rem = i - b * HW;
        int y = rem / W;
        int x = rem - y * W;
        const float* fx = flow + (size_t)(b * 2 + 0) * HW;
        const float* fy = flow + (size_t)(b * 2 + 1) * HW;
        float f00 = fx[rem], g00 = fy[rem];
        bool xe = (x + 1) < W;
        bool ye = (y + 1) < H;
        if (xe) {
            float f01 = fx[rem + 1], g01 = fy[rem + 1];
            sdx += (double)charb(f00 - f01, g00 - g01);
            if (ye) {
                float f10 = fx[rem + W], g10 = fy[rem + W];
                float f11 = fx[rem + W + 1], g11 = fy[rem + W + 1];
                sdy += (double)charb(f00 - f10, g00 - g10);
                sdr += (double)charb(f00 - f11, g00 - g11);
                sur += (double)charb(f10 - f01, g10 - g01);
            }
        } else if (ye) {
            float f10 = fx[rem + W], g10 = fy[rem + W];
            sdy += (double)charb(f00 - f10, g00 - g10);
        }
    }
    double t;
    t = blk_reduce(sdx, sm); if (threadIdx.x == 0) atomicAdd(&acc[32], t);
    t = blk_reduce(sdy, sm); if (threadIdx.x == 0) atomicAdd(&acc[33], t);
    t = blk_reduce(sdr, sm); if (threadIdx.x == 0) atomicAdd(&acc[34], t);
    t = blk_reduce(sur, sm); if (threadIdx.x == 0) atomicAdd(&acc[35], t);
}

__global__ void final_kernel(const double* __restrict__ acc,
                             float* __restrict__ out) {
    double loss = 0.0;
    for (int j = 0; j < 16; ++j) loss += acc[j] / acc[16 + j];
    double ndx = (double)B * H * (W - 1);
    double ndy = (double)B * (H - 1) * W;
    double ndd = (double)B * (H - 1) * (W - 1);
    double smooth =
        (acc[32] / ndx + acc[33] / ndy + acc[34] / ndd + acc[35] / ndd) * 0.25;
    out[0] = (float)(loss + 0.001 * smooth);
}

extern "C" void kernel_launch(void* const* d_in, const int* in_sizes, int n_in,
                              void* d_out, int out_size, void* d_ws, size_t ws_size,
                              hipStream_t stream) {
    const float* flow = (const float*)d_in[0];
    const float* ts   = (const float*)d_in[1];
    const int*   ys   = (const int*)d_in[2];
    const int*   xs   = (const int*)d_in[3];
    const int*   pol  = (const int*)d_in[4];
    float* out = (float*)d_out;

    double* acc = (double*)d_ws;
    unsigned long long* img = (unsigned long long*)((char*)d_ws + ACC_BYTES);

    // How many batches' images fit in workspace at once (last round: all 8).
    int bslots = 1;
    if (ws_size > ACC_BYTES) {
        size_t s = (ws_size - ACC_BYTES) / IMG_BYTES_PER_BATCH;
        bslots = (int)(s > 8 ? 8 : (s < 1 ? 1 : s));
    }

    hipMemsetAsync(acc, 0, ACC_BYTES, stream);
    smooth_kernel<<<4800, 256, 0, stream>>>(flow, acc);

    for (int b0 = 0; b0 < B; b0 += bslots) {
        int cnt = (B - b0) < bslots ? (B - b0) : bslots;
        hipMemsetAsync(img, 0, (size_t)cnt * IMG_BYTES_PER_BATCH, stream);
        dim3 gs((N + 255) / 256, cnt);
        splat_kernel<<<gs, 256, 0, stream>>>(flow, ts, ys, xs, pol, img, b0);
        dim3 gr(300, 2 * cnt);
        reduce_kernel<<<gr, 256, 0, stream>>>(img, acc, 2 * b0);
    }

    final_kernel<<<1, 1, 0, stream>>>(acc, out);
}

// Round 3
// 293.361 us; speedup vs baseline: 3.9459x; 2.5042x over previous
//
#include <hip/hip_runtime.h>

// EventWarping: contrast-maximization loss for event-camera flow.
// flow [B,2,H,W] f32, ts [B,N,1] f32, ys/xs/pol [B,N] i32 -> scalar f32.
//
// Round 3: global fp/u64 atomic splat (measured ceiling ~24 Gop/s at the
// device coherence point) replaced by tile binning + LDS accumulation:
//   scatter: bin (event,tref) items by 48x64 tile of warped floor pos,
//            payload packed in one u64; per-bin segments reserved with
//            LDS-aggregated global tickets (~100k atomics total).
//   accum:   1 block per (b,t,tile); replay bin into 49x65 LDS tile
//            (u32 fixed point, scale 2^18, LDS atomics). Interior pixels
//            (y%48!=0 && x%64!=0) finalized in-LDS into l/nz partial sums;
//            edge pixels flushed via global u64 atomics into a compact
//            2.9 MB line buffer (~0.5M atomics).
//   bound:   reduce the 179k line pixels.
// No 78 MB image, memset, or image re-read.

constexpr int H = 480, W = 640, HW = H * W;
constexpr int B = 8, N = 131072;
constexpr float FLOW_SCALING = 640.0f;
constexpr float EPS = 1e-9f;

constexpr int TH = 48, TW = 64;            // tile size
constexpr int TILES_Y = H / TH;            // 10
constexpr int TILES_X = W / TW;            // 10
constexpr int TILES = TILES_Y * TILES_X;   // 100
constexpr int NBINS = B * 2 * TILES;       // 1600 (b, tref, tile)
constexpr int CAP = 4096;                  // slots per bin (mean ~1310)

constexpr float PSCALE = 262144.0f;        // 2^18 fixed point in LDS tile
constexpr float PINV = 1.0f / 262144.0f;

// Boundary line buffer per job j=(b*2+t): row-lines (y%48==0): 10*640 px,
// col-lines (x%64==0, y%48!=0): 10*480 px. Each px: 2 u64 = pos(w<<32|s), neg.
constexpr int BPX = TILES_Y * W + TILES_X * H;   // 11200
// Workspace layout (all zeroed each call up to ITEMS_OFF):
//   [0)      64 doubles acc: [0..15] l per job, [16..31] nz, [32..35] smooth
//   [512)    u32 cursors[1600]
//   [8192)   u64 bnd[16][BPX][2]                (2,867,200 B)
//   [ITEMS)  u64 items[1600][CAP]               (52.4 MB)
constexpr size_t CUR_OFF = 512;
constexpr size_t BND_OFF = 8192;
constexpr size_t BND_BYTES = (size_t)16 * BPX * 2 * 8;
constexpr size_t ITEMS_OFF = BND_OFF + BND_BYTES;
constexpr size_t ZERO_BYTES = ITEMS_OFF;

__device__ inline double blk_reduce(double v, double* sm) {
    __syncthreads();
    #pragma unroll
    for (int o = 32; o > 0; o >>= 1) v += __shfl_down(v, o, 64);
    int lane = threadIdx.x & 63;
    int wid  = threadIdx.x >> 6;
    if (lane == 0) sm[wid] = v;
    __syncthreads();
    double r = 0.0;
    if (threadIdx.x == 0) {
        int nw = (int)(blockDim.x >> 6);
        for (int w2 = 0; w2 < nw; ++w2) r += sm[w2];
    }
    return r;  // thread 0 only
}

// Local bin id (tref*100 + tile) derived from the PACKED payload so that
// counting (phase A) and placement (phase C) can never disagree.
__device__ inline int bin_from_payload(unsigned long long v) {
    int t = (int)(v & 1);
    int fyi = (int)((unsigned)(v >> 40) >> 12) - 512;
    int fxi = (int)(((unsigned)(v >> 16) & 0xFFFFFFu) >> 12) - 512;
    int cy = min(max(fyi, 0), H - 1);
    int cx = min(max(fxi, 0), W - 1);
    return t * TILES + (cy / TH) * TILES_X + (cx >> 6);
}

// 512 blocks: 64 per batch, 2048 events each. Payload u64:
// [63:40] (wy+512)*4096 rn, [39:16] (wx+512)*4096 rn, [15:2] sw*16383 rn,
// [1] pol, [0] tref.  (validity filter guarantees wy,wx in [-1, 640) -> fits)
__global__ __launch_bounds__(256) void scatter_kernel(
    const float* __restrict__ flow, const float* __restrict__ ts,
    const int* __restrict__ ys, const int* __restrict__ xs,
    const int* __restrict__ pol,
    unsigned long long* __restrict__ items, unsigned* __restrict__ cursors) {
    __shared__ unsigned long long sitems[4096];   // 32 KB
    __shared__ unsigned scount[200];
    __shared__ unsigned sbase[200];
    __shared__ unsigned scur[200];
    int tid = threadIdx.x;
    for (int i = tid; i < 200; i += 256) { scount[i] = 0; scur[i] = 0; }
    __syncthreads();

    int b = blockIdx.x >> 6;
    int e0 = b * N + (blockIdx.x & 63) * 2048;
    const float* fb = flow + (size_t)b * 2 * HW;

    for (int k = 0; k < 8; ++k) {
        int ei = k * 256 + tid;
        int e = e0 + ei;
        int y = ys[e], x = xs[e], p = pol[e];
        float t0 = ts[e];
        int flat = y * W + x;
        float fx = fb[flat];
        float fy = fb[HW + flat];
        #pragma unroll
        for (int t = 0; t < 2; ++t) {
            float dt = (t == 0 ? 1.0f : 0.0f) - t0;
            float sw = (t == 0) ? t0 : 1.0f - t0;
            float wy = (float)y + dt * fy * FLOW_SCALING;
            float wx = (float)x + dt * fx * FLOW_SCALING;
            unsigned long long v = ~0ull;  // sentinel = invalid
            if (wy >= -1.0f && wy < (float)H && wx >= -1.0f && wx < (float)W) {
                unsigned uy = __float2uint_rn((wy + 512.0f) * 4096.0f);
                unsigned ux = __float2uint_rn((wx + 512.0f) * 4096.0f);
                unsigned usw = __float2uint_rn(sw * 16383.0f);
                v = ((unsigned long long)uy << 40) |
                    ((unsigned long long)ux << 16) |
                    ((unsigned long long)usw << 2) |
                    ((unsigned long long)(p != 0) << 1) |
                    (unsigned long long)t;
                atomicAdd(&scount[bin_from_payload(v)], 1u);
            }
            sitems[ei * 2 + t] = v;
        }
    }
    __syncthreads();
    if (tid < 200) {
        unsigned c = scount[tid];
        sbase[tid] = c ? atomicAdd(&cursors[b * 200 + tid], c) : 0u;
    }
    __syncthreads();
    for (int s = tid; s < 4096; s += 256) {
        unsigned long long v = sitems[s];
        if (v == ~0ull) continue;
        int binl = bin_from_payload(v);
        unsigned idx = sbase[binl] + atomicAdd(&scur[binl], 1u);
        if (idx < (unsigned)CAP)
            items[(size_t)(b * 200 + binl) * CAP + idx] = v;
    }
}

// One block per bin (b,t,tile). LDS tile 49x65, planar u32 fields
// [f][px], f: 0=w_pos 1=s_pos 2=w_neg 3=s_neg (planar -> all 32 banks used).
__global__ __launch_bounds__(256) void accum_kernel(
    const unsigned long long* __restrict__ items,
    const unsigned* __restrict__ cursors,
    unsigned long long* __restrict__ bnd, double* __restrict__ acc) {
    constexpr int TPX = (TH + 1) * (TW + 1);  // 3185
    __shared__ unsigned sacc[4 * TPX];        // 50,960 B
    __shared__ double sm[8];
    int tid = threadIdx.x;
    for (int i = tid; i < 4 * TPX; i += 256) sacc[i] = 0;
    __syncthreads();

    int bin = blockIdx.x;
    int b = bin / 200;
    int loc = bin - b * 200;
    int t = loc / TILES;
    int tile = loc - t * TILES;
    int y0 = (tile / TILES_X) * TH;
    int x0 = (tile % TILES_X) * TW;
    int cnt = (int)min(cursors[bin], (unsigned)CAP);
    const unsigned long long* bi = items + (size_t)bin * CAP;

    for (int i = tid; i < cnt; i += 256) {
        unsigned long long v = bi[i];
        unsigned uy = (unsigned)(v >> 40);
        unsigned ux = (unsigned)(v >> 16) & 0xFFFFFFu;
        float wy = (float)uy * (1.0f / 4096.0f) - 512.0f;
        float wx = (float)ux * (1.0f / 4096.0f) - 512.0f;
        int fyi = (int)(uy >> 12) - 512;
        int fxi = (int)(ux >> 12) - 512;
        float sw = (float)((unsigned)(v >> 2) & 0x3FFFu) * (1.0f / 16383.0f);
        int f = ((v >> 1) & 1) ? 0 : 2;  // pol=1 -> pos fields
        #pragma unroll
        for (int dy = 0; dy < 2; ++dy) {
            int ry = fyi + dy, ly = ry - y0;
            if (ry < 0 || ry >= H || ly < 0 || ly > TH) continue;
            float wfy = 1.0f - fabsf(wy - (float)ry);
            #pragma unroll
            for (int dx = 0; dx < 2; ++dx) {
                int rx = fxi + dx, lx = rx - x0;
                if (rx < 0 || rx >= W || lx < 0 || lx > TW) continue;
                float wgt = wfy * (1.0f - fabsf(wx - (float)rx));
                int px = ly * (TW + 1) + lx;
                atomicAdd(&sacc[f * TPX + px], __float2uint_rn(wgt * PSCALE));
                atomicAdd(&sacc[(f + 1) * TPX + px],
                          __float2uint_rn(wgt * sw * PSCALE));
            }
        }
    }
    __syncthreads();

    // Interior pixels finalize locally; tile-edge pixels (y%48==0 row-lines,
    // else x%64==0 col-lines) merge via global atomics into the line buffer.
    double l = 0.0, nz = 0.0;
    unsigned long long* bj = bnd + (size_t)(b * 2 + t) * BPX * 2;
    for (int p = tid; p < TPX; p += 256) {
        int ly = p / (TW + 1), lx = p - ly * (TW + 1);
        int y = y0 + ly, x = x0 + lx;
        if (y >= H || x >= W) continue;
        unsigned wp = sacc[0 * TPX + p], sp = sacc[1 * TPX + p];
        unsigned wn = sacc[2 * TPX + p], sn = sacc[3 * TPX + p];
        if (ly == 0 || ly == TH) {
            int off = (y / TH) * W + x;
            if (wp | sp)
                atomicAdd(&bj[(size_t)off * 2],
                          ((unsigned long long)wp << 32) | sp);
            if (wn | sn)
                atomicAdd(&bj[(size_t)off * 2 + 1],
                          ((unsigned long long)wn << 32) | sn);
        } else if (lx == 0 || lx == TW) {
            int off = TILES_Y * W + (x >> 6) * H + y;
            if (wp | sp)
                atomicAdd(&bj[(size_t)off * 2],
                          ((unsigned long long)wp << 32) | sp);
            if (wn | sn)
                atomicAdd(&bj[(size_t)off * 2 + 1],
                          ((unsigned long long)wn << 32) | sn);
        } else {
            float fwp = (float)wp * PINV, fsp = (float)sp * PINV;
            float fwn = (float)wn * PINV, fsn = (float)sn * PINV;
            float a = fsp / (fwp + EPS);
            float c = fsn / (fwn + EPS);
            l += (double)(a * a + c * c);
            if (wp | wn) nz += 1.0;
        }
    }
    double lt = blk_reduce(l, sm);
    double nt = blk_reduce(nz, sm);
    if (tid == 0) {
        atomicAdd(&acc[b * 2 + t], lt);
        atomicAdd(&acc[16 + b * 2 + t], nt);
    }
}

// Reduce the line buffer. grid (44, 16): one y-slice per job j.
// Col-line slots with y%48==0 are never written (rule sends them to the
// row-line) -> stay zero -> contribute nothing (no double count).
__global__ __launch_bounds__(256) void bound_kernel(
    const unsigned long long* __restrict__ bnd, double* __restrict__ acc) {
    __shared__ double sm[8];
    int j = blockIdx.y;
    double l = 0.0, nz = 0.0;
    for (int p = blockIdx.x * blockDim.x + threadIdx.x; p < BPX;
         p += gridDim.x * blockDim.x) {
        unsigned long long vp = bnd[((size_t)j * BPX + p) * 2];
        unsigned long long vn = bnd[((size_t)j * BPX + p) * 2 + 1];
        unsigned wp = (unsigned)(vp >> 32), sp = (unsigned)vp;
        unsigned wn = (unsigned)(vn >> 32), sn = (unsigned)vn;
        float a = ((float)sp * PINV) / ((float)wp * PINV + EPS);
        float c = ((float)sn * PINV) / ((float)wn * PINV + EPS);
        l += (double)(a * a + c * c);
        if (wp | wn) nz += 1.0;
    }
    double lt = blk_reduce(l, sm);
    double nt = blk_reduce(nz, sm);
    if (threadIdx.x == 0) {
        atomicAdd(&acc[j], lt);
        atomicAdd(&acc[16 + j], nt);
    }
}

__device__ inline float charb(float a, float b) {
    return sqrtf(a * a + b * b + 1e-6f);
}

__global__ __launch_bounds__(256) void smooth_kernel(
    const float* __restrict__ flow, double* __restrict__ acc) {
    __shared__ double sm[8];
    double sdx = 0.0, sdy = 0.0, sdr = 0.0, sur = 0.0;
    int stride = gridDim.x * blockDim.x;
    for (int i = blockIdx.x * blockDim.x + threadIdx.x; i < B * HW; i += stride) {
        int b = i / HW;
        int rem = i - b * HW;
        int y = rem / W;
        int x = rem - y * W;
        const float* fx = flow + (size_t)(b * 2 + 0) * HW;
        const float* fy = flow + (size_t)(b * 2 + 1) * HW;
        float f00 = fx[rem], g00 = fy[rem];
        bool xe = (x + 1) < W;
        bool ye = (y + 1) < H;
        if (xe) {
            float f01 = fx[rem + 1], g01 = fy[rem + 1];
            sdx += (double)charb(f00 - f01, g00 - g01);
            if (ye) {
                float f10 = fx[rem + W], g10 = fy[rem + W];
                float f11 = fx[rem + W + 1], g11 = fy[rem + W + 1];
                sdy += (double)charb(f00 - f10, g00 - g10);
                sdr += (double)charb(f00 - f11, g00 - g11);
                sur += (double)charb(f10 - f01, g10 - g01);
            }
        } else if (ye) {
            float f10 = fx[rem + W], g10 = fy[rem + W];
            sdy += (double)charb(f00 - f10, g00 - g10);
        }
    }
    double tt;
    tt = blk_reduce(sdx, sm); if (threadIdx.x == 0) atomicAdd(&acc[32], tt);
    tt = blk_reduce(sdy, sm); if (threadIdx.x == 0) atomicAdd(&acc[33], tt);
    tt = blk_reduce(sdr, sm); if (threadIdx.x == 0) atomicAdd(&acc[34], tt);
    tt = blk_reduce(sur, sm); if (threadIdx.x == 0) atomicAdd(&acc[35], tt);
}

__global__ void final_kernel(const double* __restrict__ acc,
                             float* __restrict__ out) {
    double loss = 0.0;
    for (int j = 0; j < 16; ++j) loss += acc[j] / acc[16 + j];
    double ndx = (double)B * H * (W - 1);
    double ndy = (double)B * (H - 1) * W;
    double ndd = (double)B * (H - 1) * (W - 1);
    double smooth =
        (acc[32] / ndx + acc[33] / ndy + acc[34] / ndd + acc[35] / ndd) * 0.25;
    out[0] = (float)(loss + 0.001 * smooth);
}

extern "C" void kernel_launch(void* const* d_in, const int* in_sizes, int n_in,
                              void* d_out, int out_size, void* d_ws, size_t ws_size,
                              hipStream_t stream) {
    const float* flow = (const float*)d_in[0];
    const float* ts   = (const float*)d_in[1];
    const int*   ys   = (const int*)d_in[2];
    const int*   xs   = (const int*)d_in[3];
    const int*   pol  = (const int*)d_in[4];
    float* out = (float*)d_out;

    double* acc = (double*)d_ws;
    unsigned* cursors = (unsigned*)((char*)d_ws + CUR_OFF);
    unsigned long long* bnd = (unsigned long long*)((char*)d_ws + BND_OFF);
    unsigned long long* items = (unsigned long long*)((char*)d_ws + ITEMS_OFF);

    hipMemsetAsync(d_ws, 0, ZERO_BYTES, stream);
    smooth_kernel<<<2400, 256, 0, stream>>>(flow, acc);
    scatter_kernel<<<512, 256, 0, stream>>>(flow, ts, ys, xs, pol, items, cursors);
    accum_kernel<<<NBINS, 256, 0, stream>>>(items, cursors, bnd, acc);
    bound_kernel<<<dim3(44, 16), 256, 0, stream>>>(bnd, acc);
    final_kernel<<<1, 1, 0, stream>>>(acc, out);
}

// Round 4
// 178.615 us; speedup vs baseline: 6.4809x; 1.6424x over previous
//
#include <hip/hip_runtime.h>

// EventWarping: contrast-maximization loss for event-camera flow.
// flow [B,2,H,W] f32, ts [B,N,1] f32, ys/xs/pol [B,N] i32 -> scalar f32.
//
// Round 4: round-3 profile showed smooth_kernel at 126us — fp64 global
// atomicAdd (CAS-loop) with 9600 contenders on 4 addresses serialized at
// the coherence point (HBM 2%, VALU 7%). ALL fp64 global atomics removed:
// every reducing kernel writes block-partials to distinct slots; one
// final_kernel reduces everything. Splat path unchanged from round 3
// (tile binning + LDS accumulation).

constexpr int H = 480, W = 640, HW = H * W;
constexpr int B = 8, N = 131072;
constexpr float FLOW_SCALING = 640.0f;
constexpr float EPS = 1e-9f;

constexpr int TH = 48, TW = 64;            // tile size
constexpr int TILES_Y = H / TH;            // 10
constexpr int TILES_X = W / TW;            // 10
constexpr int TILES = TILES_Y * TILES_X;   // 100
constexpr int NBINS = B * 2 * TILES;       // 1600 (b, tref, tile)
constexpr int CAP = 4096;                  // slots per bin (mean ~1310)

constexpr float PSCALE = 262144.0f;        // 2^18 fixed point in LDS tile
constexpr float PINV = 1.0f / 262144.0f;

constexpr int BND_BLK = 44;                // bound_kernel grid.x
constexpr int SM_BLK = 512;                // smooth_kernel grid

// Boundary line buffer per job j=(b*2+t): row-lines (y%48==0): 10*640 px,
// col-lines (x%64==0, y%48!=0): 10*480 px. Each px: 2 u64 = pos(w<<32|s), neg.
constexpr int BPX = TILES_Y * W + TILES_X * H;   // 11200

// Workspace layout (doubles unless noted):
//   accL[16][100], accN[16][100]   : accum per-(job,tile) partials
//   bndL[16][44],  bndN[16][44]    : bound per-(job,block) partials
//   smP[512][4]                    : smooth per-block partials dx,dy,dr,ur
//   cursors u32[1600]
//   bnd u64[16][BPX][2]            : line buffer (zeroed)
//   items u64[1600][CAP]
constexpr size_t ACCL_OFF = 0;
constexpr size_t ACCN_OFF = ACCL_OFF + (size_t)16 * TILES * 8;       // 12800
constexpr size_t BNDL_OFF = ACCN_OFF + (size_t)16 * TILES * 8;       // 25600
constexpr size_t BNDN_OFF = BNDL_OFF + (size_t)16 * BND_BLK * 8;     // 31232
constexpr size_t SMP_OFF  = BNDN_OFF + (size_t)16 * BND_BLK * 8;     // 36864
constexpr size_t CUR_OFF  = SMP_OFF + (size_t)SM_BLK * 4 * 8;        // 53248
constexpr size_t BND_OFF  = CUR_OFF + (size_t)NBINS * 4;             // 59648
constexpr size_t BND_BYTES = (size_t)16 * BPX * 2 * 8;               // 2867200
constexpr size_t ITEMS_OFF = BND_OFF + BND_BYTES;

__device__ inline double blk_reduce(double v, double* sm) {
    __syncthreads();
    #pragma unroll
    for (int o = 32; o > 0; o >>= 1) v += __shfl_down(v, o, 64);
    int lane = threadIdx.x & 63;
    int wid  = threadIdx.x >> 6;
    if (lane == 0) sm[wid] = v;
    __syncthreads();
    double r = 0.0;
    if (threadIdx.x == 0) {
        int nw = (int)(blockDim.x >> 6);
        for (int w2 = 0; w2 < nw; ++w2) r += sm[w2];
    }
    return r;  // thread 0 only
}

// Local bin id (tref*100 + tile) derived from the PACKED payload so that
// counting (phase A) and placement (phase C) can never disagree.
__device__ inline int bin_from_payload(unsigned long long v) {
    int t = (int)(v & 1);
    int fyi = (int)((unsigned)(v >> 40) >> 12) - 512;
    int fxi = (int)(((unsigned)(v >> 16) & 0xFFFFFFu) >> 12) - 512;
    int cy = min(max(fyi, 0), H - 1);
    int cx = min(max(fxi, 0), W - 1);
    return t * TILES + (cy / TH) * TILES_X + (cx >> 6);
}

// 512 blocks: 64 per batch, 2048 events each. Payload u64:
// [63:40] (wy+512)*4096 rn, [39:16] (wx+512)*4096 rn, [15:2] sw*16383 rn,
// [1] pol, [0] tref.  (validity filter guarantees wy,wx in [-1, 640) -> fits)
__global__ __launch_bounds__(256) void scatter_kernel(
    const float* __restrict__ flow, const float* __restrict__ ts,
    const int* __restrict__ ys, const int* __restrict__ xs,
    const int* __restrict__ pol,
    unsigned long long* __restrict__ items, unsigned* __restrict__ cursors) {
    __shared__ unsigned long long sitems[4096];   // 32 KB
    __shared__ unsigned scount[200];
    __shared__ unsigned sbase[200];
    __shared__ unsigned scur[200];
    int tid = threadIdx.x;
    for (int i = tid; i < 200; i += 256) { scount[i] = 0; scur[i] = 0; }
    __syncthreads();

    int b = blockIdx.x >> 6;
    int e0 = b * N + (blockIdx.x & 63) * 2048;
    const float* fb = flow + (size_t)b * 2 * HW;

    for (int k = 0; k < 8; ++k) {
        int ei = k * 256 + tid;
        int e = e0 + ei;
        int y = ys[e], x = xs[e], p = pol[e];
        float t0 = ts[e];
        int flat = y * W + x;
        float fx = fb[flat];
        float fy = fb[HW + flat];
        #pragma unroll
        for (int t = 0; t < 2; ++t) {
            float dt = (t == 0 ? 1.0f : 0.0f) - t0;
            float sw = (t == 0) ? t0 : 1.0f - t0;
            float wy = (float)y + dt * fy * FLOW_SCALING;
            float wx = (float)x + dt * fx * FLOW_SCALING;
            unsigned long long v = ~0ull;  // sentinel = invalid
            if (wy >= -1.0f && wy < (float)H && wx >= -1.0f && wx < (float)W) {
                unsigned uy = __float2uint_rn((wy + 512.0f) * 4096.0f);
                unsigned ux = __float2uint_rn((wx + 512.0f) * 4096.0f);
                unsigned usw = __float2uint_rn(sw * 16383.0f);
                v = ((unsigned long long)uy << 40) |
                    ((unsigned long long)ux << 16) |
                    ((unsigned long long)usw << 2) |
                    ((unsigned long long)(p != 0) << 1) |
                    (unsigned long long)t;
                atomicAdd(&scount[bin_from_payload(v)], 1u);
            }
            sitems[ei * 2 + t] = v;
        }
    }
    __syncthreads();
    if (tid < 200) {
        unsigned c = scount[tid];
        sbase[tid] = c ? atomicAdd(&cursors[b * 200 + tid], c) : 0u;
    }
    __syncthreads();
    for (int s = tid; s < 4096; s += 256) {
        unsigned long long v = sitems[s];
        if (v == ~0ull) continue;
        int binl = bin_from_payload(v);
        unsigned idx = sbase[binl] + atomicAdd(&scur[binl], 1u);
        if (idx < (unsigned)CAP)
            items[(size_t)(b * 200 + binl) * CAP + idx] = v;
    }
}

// One block per bin (b,t,tile). LDS tile 49x65, planar u32 fields
// [f][px], f: 0=w_pos 1=s_pos 2=w_neg 3=s_neg.
__global__ __launch_bounds__(256) void accum_kernel(
    const unsigned long long* __restrict__ items,
    const unsigned* __restrict__ cursors,
    unsigned long long* __restrict__ bnd,
    double* __restrict__ accL, double* __restrict__ accN) {
    constexpr int TPX = (TH + 1) * (TW + 1);  // 3185
    __shared__ unsigned sacc[4 * TPX];        // 50,960 B
    __shared__ double sm[8];
    int tid = threadIdx.x;
    for (int i = tid; i < 4 * TPX; i += 256) sacc[i] = 0;
    __syncthreads();

    int bin = blockIdx.x;
    int b = bin / 200;
    int loc = bin - b * 200;
    int t = loc / TILES;
    int tile = loc - t * TILES;
    int y0 = (tile / TILES_X) * TH;
    int x0 = (tile % TILES_X) * TW;
    int cnt = (int)min(cursors[bin], (unsigned)CAP);
    const unsigned long long* bi = items + (size_t)bin * CAP;

    for (int i = tid; i < cnt; i += 256) {
        unsigned long long v = bi[i];
        unsigned uy = (unsigned)(v >> 40);
        unsigned ux = (unsigned)(v >> 16) & 0xFFFFFFu;
        float wy = (float)uy * (1.0f / 4096.0f) - 512.0f;
        float wx = (float)ux * (1.0f / 4096.0f) - 512.0f;
        int fyi = (int)(uy >> 12) - 512;
        int fxi = (int)(ux >> 12) - 512;
        float sw = (float)((unsigned)(v >> 2) & 0x3FFFu) * (1.0f / 16383.0f);
        int f = ((v >> 1) & 1) ? 0 : 2;  // pol=1 -> pos fields
        #pragma unroll
        for (int dy = 0; dy < 2; ++dy) {
            int ry = fyi + dy, ly = ry - y0;
            if (ry < 0 || ry >= H || ly < 0 || ly > TH) continue;
            float wfy = 1.0f - fabsf(wy - (float)ry);
            #pragma unroll
            for (int dx = 0; dx < 2; ++dx) {
                int rx = fxi + dx, lx = rx - x0;
                if (rx < 0 || rx >= W || lx < 0 || lx > TW) continue;
                float wgt = wfy * (1.0f - fabsf(wx - (float)rx));
                int px = ly * (TW + 1) + lx;
                atomicAdd(&sacc[f * TPX + px], __float2uint_rn(wgt * PSCALE));
                atomicAdd(&sacc[(f + 1) * TPX + px],
                          __float2uint_rn(wgt * sw * PSCALE));
            }
        }
    }
    __syncthreads();

    // Interior pixels finalize locally; tile-edge pixels (y%48==0 row-lines,
    // else x%64==0 col-lines) merge via global u64 atomics into line buffer.
    double l = 0.0, nz = 0.0;
    unsigned long long* bj = bnd + (size_t)(b * 2 + t) * BPX * 2;
    for (int p = tid; p < TPX; p += 256) {
        int ly = p / (TW + 1), lx = p - ly * (TW + 1);
        int y = y0 + ly, x = x0 + lx;
        if (y >= H || x >= W) continue;
        unsigned wp = sacc[0 * TPX + p], sp = sacc[1 * TPX + p];
        unsigned wn = sacc[2 * TPX + p], sn = sacc[3 * TPX + p];
        if (ly == 0 || ly == TH) {
            int off = (y / TH) * W + x;
            if (wp | sp)
                atomicAdd(&bj[(size_t)off * 2],
                          ((unsigned long long)wp << 32) | sp);
            if (wn | sn)
                atomicAdd(&bj[(size_t)off * 2 + 1],
                          ((unsigned long long)wn << 32) | sn);
        } else if (lx == 0 || lx == TW) {
            int off = TILES_Y * W + (x >> 6) * H + y;
            if (wp | sp)
                atomicAdd(&bj[(size_t)off * 2],
                          ((unsigned long long)wp << 32) | sp);
            if (wn | sn)
                atomicAdd(&bj[(size_t)off * 2 + 1],
                          ((unsigned long long)wn << 32) | sn);
        } else {
            float fwp = (float)wp * PINV, fsp = (float)sp * PINV;
            float fwn = (float)wn * PINV, fsn = (float)sn * PINV;
            float a = fsp / (fwp + EPS);
            float c = fsn / (fwn + EPS);
            l += (double)(a * a + c * c);
            if (wp | wn) nz += 1.0;
        }
    }
    double lt = blk_reduce(l, sm);
    double nt = blk_reduce(nz, sm);
    if (tid == 0) {
        int j = b * 2 + t;
        accL[j * TILES + tile] = lt;   // distinct slot: NO atomics
        accN[j * TILES + tile] = nt;
    }
}

// Reduce the line buffer. grid (44, 16). Col-line slots with y%48==0 are
// never written -> zero -> no double count.
__global__ __launch_bounds__(256) void bound_kernel(
    const unsigned long long* __restrict__ bnd,
    double* __restrict__ bndL, double* __restrict__ bndN) {
    __shared__ double sm[8];
    int j = blockIdx.y;
    double l = 0.0, nz = 0.0;
    for (int p = blockIdx.x * blockDim.x + threadIdx.x; p < BPX;
         p += gridDim.x * blockDim.x) {
        unsigned long long vp = bnd[((size_t)j * BPX + p) * 2];
        unsigned long long vn = bnd[((size_t)j * BPX + p) * 2 + 1];
        unsigned wp = (unsigned)(vp >> 32), sp = (unsigned)vp;
        unsigned wn = (unsigned)(vn >> 32), sn = (unsigned)vn;
        float a = ((float)sp * PINV) / ((float)wp * PINV + EPS);
        float c = ((float)sn * PINV) / ((float)wn * PINV + EPS);
        l += (double)(a * a + c * c);
        if (wp | wn) nz += 1.0;
    }
    double lt = blk_reduce(l, sm);
    double nt = blk_reduce(nz, sm);
    if (threadIdx.x == 0) {
        bndL[j * BND_BLK + blockIdx.x] = lt;
        bndN[j * BND_BLK + blockIdx.x] = nt;
    }
}

__device__ inline float charb(float a, float b) {
    return sqrtf(a * a + b * b + 1e-6f);
}

__global__ __launch_bounds__(256) void smooth_kernel(
    const float* __restrict__ flow, double* __restrict__ smP) {
    __shared__ double sm[8];
    double sdx = 0.0, sdy = 0.0, sdr = 0.0, sur = 0.0;
    int stride = gridDim.x * blockDim.x;
    for (int i = blockIdx.x * blockDim.x + threadIdx.x; i < B * HW; i += stride) {
        int b = i / HW;
        int rem = i - b * HW;
        int y = rem / W;
        int x = rem - y * W;
        const float* fx = flow + (size_t)(b * 2 + 0) * HW;
        const float* fy = flow + (size_t)(b * 2 + 1) * HW;
        float f00 = fx[rem], g00 = fy[rem];
        bool xe = (x + 1) < W;
        bool ye = (y + 1) < H;
        if (xe) {
            float f01 = fx[rem + 1], g01 = fy[rem + 1];
            sdx += (double)charb(f00 - f01, g00 - g01);
            if (ye) {
                float f10 = fx[rem + W], g10 = fy[rem + W];
                float f11 = fx[rem + W + 1], g11 = fy[rem + W + 1];
                sdy += (double)charb(f00 - f10, g00 - g10);
                sdr += (double)charb(f00 - f11, g00 - g11);
                sur += (double)charb(f10 - f01, g10 - g01);
            }
        } else if (ye) {
            float f10 = fx[rem + W], g10 = fy[rem + W];
            sdy += (double)charb(f00 - f10, g00 - g10);
        }
    }
    double tt;
    tt = blk_reduce(sdx, sm); if (threadIdx.x == 0) smP[blockIdx.x * 4 + 0] = tt;
    tt = blk_reduce(sdy, sm); if (threadIdx.x == 0) smP[blockIdx.x * 4 + 1] = tt;
    tt = blk_reduce(sdr, sm); if (threadIdx.x == 0) smP[blockIdx.x * 4 + 2] = tt;
    tt = blk_reduce(sur, sm); if (threadIdx.x == 0) smP[blockIdx.x * 4 + 3] = tt;
}

// One block, 256 threads. 16 threads per job reduce accL/accN + bndL/bndN
// (width-16 shfl); whole block reduces the 4 smooth components.
__global__ __launch_bounds__(256) void final_kernel(
    const double* __restrict__ accL, const double* __restrict__ accN,
    const double* __restrict__ bndL, const double* __restrict__ bndN,
    const double* __restrict__ smP, float* __restrict__ out) {
    __shared__ double sj[16];
    __shared__ double sm[8];
    int tid = threadIdx.x;
    int j = tid >> 4, s = tid & 15;
    double l = 0.0, nz = 0.0;
    for (int i = s; i < TILES; i += 16) {
        l += accL[j * TILES + i];
        nz += accN[j * TILES + i];
    }
    for (int i = s; i < BND_BLK; i += 16) {
        l += bndL[j * BND_BLK + i];
        nz += bndN[j * BND_BLK + i];
    }
    #pragma unroll
    for (int o = 8; o > 0; o >>= 1) {
        l += __shfl_down(l, o, 16);
        nz += __shfl_down(nz, o, 16);
    }
    if (s == 0) sj[j] = l / nz;

    double c[4] = {0.0, 0.0, 0.0, 0.0};
    for (int i = tid; i < SM_BLK; i += 256) {
        #pragma unroll
        for (int k = 0; k < 4; ++k) c[k] += smP[i * 4 + k];
    }
    double s0 = blk_reduce(c[0], sm);
    double s1 = blk_reduce(c[1], sm);
    double s2 = blk_reduce(c[2], sm);
    double s3 = blk_reduce(c[3], sm);
    __syncthreads();
    if (tid == 0) {
        double loss = 0.0;
        for (int q = 0; q < 16; ++q) loss += sj[q];
        double ndx = (double)B * H * (W - 1);
        double ndy = (double)B * (H - 1) * W;
        double ndd = (double)B * (H - 1) * (W - 1);
        double smooth = (s0 / ndx + s1 / ndy + s2 / ndd + s3 / ndd) * 0.25;
        out[0] = (float)(loss + 0.001 * smooth);
    }
}

extern "C" void kernel_launch(void* const* d_in, const int* in_sizes, int n_in,
                              void* d_out, int out_size, void* d_ws, size_t ws_size,
                              hipStream_t stream) {
    const float* flow = (const float*)d_in[0];
    const float* ts   = (const float*)d_in[1];
    const int*   ys   = (const int*)d_in[2];
    const int*   xs   = (const int*)d_in[3];
    const int*   pol  = (const int*)d_in[4];
    float* out = (float*)d_out;

    char* ws = (char*)d_ws;
    double* accL = (double*)(ws + ACCL_OFF);
    double* accN = (double*)(ws + ACCN_OFF);
    double* bndL = (double*)(ws + BNDL_OFF);
    double* bndN = (double*)(ws + BNDN_OFF);
    double* smP  = (double*)(ws + SMP_OFF);
    unsigned* cursors = (unsigned*)(ws + CUR_OFF);
    unsigned long long* bnd = (unsigned long long*)(ws + BND_OFF);
    unsigned long long* items = (unsigned long long*)(ws + ITEMS_OFF);

    // cursors + line buffer must start at zero (partial arrays are fully
    // written by their producers — no zeroing needed).
    hipMemsetAsync(ws + CUR_OFF, 0, ITEMS_OFF - CUR_OFF, stream);
    smooth_kernel<<<SM_BLK, 256, 0, stream>>>(flow, smP);
    scatter_kernel<<<512, 256, 0, stream>>>(flow, ts, ys, xs, pol, items, cursors);
    accum_kernel<<<NBINS, 256, 0, stream>>>(items, cursors, bnd, accL, accN);
    bound_kernel<<<dim3(BND_BLK, 16), 256, 0, stream>>>(bnd, bndL, bndN);
    final_kernel<<<1, 256, 0, stream>>>(accL, accN, bndL, bndN, smP, out);
}

// Round 5
// 158.983 us; speedup vs baseline: 7.2811x; 1.1235x over previous
//
#include <hip/hip_runtime.h>

// EventWarping: contrast-maximization loss for event-camera flow.
// flow [B,2,H,W] f32, ts [B,N,1] f32, ys/xs/pol [B,N] i32 -> scalar f32.
//
// Round 5: scatter was top (44us, FETCH 112MB vs 36MB inputs, occ 17%):
//  - payloads now live in registers (no 32KB LDS staging) -> 2.4KB LDS,
//    1024 blocks (1024 ev each) for latency hiding;
//  - batches XCD-pinned (b = blockIdx&7) so each batch's 2.46MB flow is
//    cached by one XCD L2 instead of replicated 8x (heuristic: round-robin
//    blockIdx->XCD; worst case neutral).
//  - accum: one u64 LDS atomic per corner (w<<32|s, 2^18 fixed point)
//    instead of two u32 atomics. Per-tile w-sum <= CAP*2^18 = 2^30: no carry.

constexpr int H = 480, W = 640, HW = H * W;
constexpr int B = 8, N = 131072;
constexpr float FLOW_SCALING = 640.0f;
constexpr float EPS = 1e-9f;

constexpr int TH = 48, TW = 64;            // tile size
constexpr int TILES_Y = H / TH;            // 10
constexpr int TILES_X = W / TW;            // 10
constexpr int TILES = TILES_Y * TILES_X;   // 100
constexpr int NBINS = B * 2 * TILES;       // 1600 (b, tref, tile)
constexpr int CAP = 4096;                  // slots per bin (mean ~1310)

constexpr float PSCALE = 262144.0f;        // 2^18 fixed point
constexpr float PINV = 1.0f / 262144.0f;

constexpr int BND_BLK = 44;                // bound_kernel grid.x
constexpr int SM_BLK = 512;                // smooth_kernel grid
constexpr int SC_BLOCKS = 1024;            // scatter grid (128 per batch)

// Boundary line buffer per job j=(b*2+t): row-lines (y%48==0): 10*640 px,
// col-lines (x%64==0, y%48!=0): 10*480 px. Each px: 2 u64 = pos(w<<32|s), neg.
constexpr int BPX = TILES_Y * W + TILES_X * H;   // 11200

// Workspace layout:
//   accL[16][100], accN[16][100]   : accum per-(job,tile) partials (f64)
//   bndL[16][44],  bndN[16][44]    : bound per-(job,block) partials
//   smP[512][4]                    : smooth per-block partials dx,dy,dr,ur
//   cursors u32[1600]
//   bnd u64[16][BPX][2]            : line buffer (zeroed)
//   items u64[1600][CAP]
constexpr size_t ACCL_OFF = 0;
constexpr size_t ACCN_OFF = ACCL_OFF + (size_t)16 * TILES * 8;       // 12800
constexpr size_t BNDL_OFF = ACCN_OFF + (size_t)16 * TILES * 8;       // 25600
constexpr size_t BNDN_OFF = BNDL_OFF + (size_t)16 * BND_BLK * 8;     // 31232
constexpr size_t SMP_OFF  = BNDN_OFF + (size_t)16 * BND_BLK * 8;     // 36864
constexpr size_t CUR_OFF  = SMP_OFF + (size_t)SM_BLK * 4 * 8;        // 53248
constexpr size_t BND_OFF  = CUR_OFF + (size_t)NBINS * 4;             // 59648
constexpr size_t BND_BYTES = (size_t)16 * BPX * 2 * 8;               // 2867200
constexpr size_t ITEMS_OFF = BND_OFF + BND_BYTES;

__device__ inline double blk_reduce(double v, double* sm) {
    __syncthreads();
    #pragma unroll
    for (int o = 32; o > 0; o >>= 1) v += __shfl_down(v, o, 64);
    int lane = threadIdx.x & 63;
    int wid  = threadIdx.x >> 6;
    if (lane == 0) sm[wid] = v;
    __syncthreads();
    double r = 0.0;
    if (threadIdx.x == 0) {
        int nw = (int)(blockDim.x >> 6);
        for (int w2 = 0; w2 < nw; ++w2) r += sm[w2];
    }
    return r;  // thread 0 only
}

// Local bin id (tref*100 + tile) from the PACKED payload, so count and
// placement phases can never disagree.
__device__ inline int bin_from_payload(unsigned long long v) {
    int t = (int)(v & 1);
    int fyi = (int)((unsigned)(v >> 40) >> 12) - 512;
    int fxi = (int)(((unsigned)(v >> 16) & 0xFFFFFFu) >> 12) - 512;
    int cy = min(max(fyi, 0), H - 1);
    int cx = min(max(fxi, 0), W - 1);
    return t * TILES + (cy / TH) * TILES_X + (cx >> 6);
}

// 1024 blocks; batch = blockIdx&7 (XCD pin), 1024 events per block, payloads
// in registers. Payload u64: [63:40] (wy+512)*4096 rn, [39:16] (wx+512)*4096,
// [15:2] sw*16383 rn, [1] pol, [0] tref. Validity filter keeps coords in range.
__global__ __launch_bounds__(256) void scatter_kernel(
    const float* __restrict__ flow, const float* __restrict__ ts,
    const int* __restrict__ ys, const int* __restrict__ xs,
    const int* __restrict__ pol,
    unsigned long long* __restrict__ items, unsigned* __restrict__ cursors) {
    __shared__ unsigned scount[200];
    __shared__ unsigned sbase[200];
    __shared__ unsigned scur[200];
    int tid = threadIdx.x;
    if (tid < 200) { scount[tid] = 0; scur[tid] = 0; }
    __syncthreads();

    int b = blockIdx.x & 7;
    int chunk = blockIdx.x >> 3;          // 0..127
    int e0 = b * N + chunk * 1024;
    const float* fb = flow + (size_t)b * 2 * HW;

    unsigned long long pay[8];
    #pragma unroll
    for (int k = 0; k < 4; ++k) {
        int e = e0 + k * 256 + tid;
        int y = ys[e], x = xs[e], p = pol[e];
        float t0 = ts[e];
        int flat = y * W + x;
        float fx = fb[flat];
        float fy = fb[HW + flat];
        #pragma unroll
        for (int t = 0; t < 2; ++t) {
            float dt = (t == 0 ? 1.0f : 0.0f) - t0;
            float sw = (t == 0) ? t0 : 1.0f - t0;
            float wy = (float)y + dt * fy * FLOW_SCALING;
            float wx = (float)x + dt * fx * FLOW_SCALING;
            unsigned long long v = ~0ull;  // sentinel = invalid
            if (wy >= -1.0f && wy < (float)H && wx >= -1.0f && wx < (float)W) {
                unsigned uy = __float2uint_rn((wy + 512.0f) * 4096.0f);
                unsigned ux = __float2uint_rn((wx + 512.0f) * 4096.0f);
                unsigned usw = __float2uint_rn(sw * 16383.0f);
                v = ((unsigned long long)uy << 40) |
                    ((unsigned long long)ux << 16) |
                    ((unsigned long long)usw << 2) |
                    ((unsigned long long)(p != 0) << 1) |
                    (unsigned long long)t;
                atomicAdd(&scount[bin_from_payload(v)], 1u);
            }
            pay[k * 2 + t] = v;
        }
    }
    __syncthreads();
    if (tid < 200) {
        unsigned c = scount[tid];
        sbase[tid] = c ? atomicAdd(&cursors[b * 200 + tid], c) : 0u;
    }
    __syncthreads();
    #pragma unroll
    for (int i = 0; i < 8; ++i) {
        unsigned long long v = pay[i];
        if (v == ~0ull) continue;
        int binl = bin_from_payload(v);
        unsigned idx = sbase[binl] + atomicAdd(&scur[binl], 1u);
        if (idx < (unsigned)CAP)
            items[(size_t)(b * 200 + binl) * CAP + idx] = v;
    }
}

// One block per bin (b,t,tile). LDS tile 49x65, u64 per pixel per polarity
// field (0=pos, 1=neg), each packing (w<<32 | s) at 2^18 fixed point.
__global__ __launch_bounds__(256) void accum_kernel(
    const unsigned long long* __restrict__ items,
    const unsigned* __restrict__ cursors,
    unsigned long long* __restrict__ bnd,
    double* __restrict__ accL, double* __restrict__ accN) {
    constexpr int TPX = (TH + 1) * (TW + 1);      // 3185
    __shared__ unsigned long long sacc[2 * TPX];  // 50,960 B
    __shared__ double sm[8];
    int tid = threadIdx.x;
    for (int i = tid; i < 2 * TPX; i += 256) sacc[i] = 0ull;
    __syncthreads();

    int bin = blockIdx.x;
    int b = bin / 200;
    int loc = bin - b * 200;
    int t = loc / TILES;
    int tile = loc - t * TILES;
    int y0 = (tile / TILES_X) * TH;
    int x0 = (tile % TILES_X) * TW;
    int cnt = (int)min(cursors[bin], (unsigned)CAP);
    const unsigned long long* bi = items + (size_t)bin * CAP;

    for (int i = tid; i < cnt; i += 256) {
        unsigned long long v = bi[i];
        unsigned uy = (unsigned)(v >> 40);
        unsigned ux = (unsigned)(v >> 16) & 0xFFFFFFu;
        float wy = (float)uy * (1.0f / 4096.0f) - 512.0f;
        float wx = (float)ux * (1.0f / 4096.0f) - 512.0f;
        int fyi = (int)(uy >> 12) - 512;
        int fxi = (int)(ux >> 12) - 512;
        float sw = (float)((unsigned)(v >> 2) & 0x3FFFu) * (1.0f / 16383.0f);
        int f = ((v >> 1) & 1) ? 0 : 1;  // pol=1 -> pos field
        #pragma unroll
        for (int dy = 0; dy < 2; ++dy) {
            int ry = fyi + dy, ly = ry - y0;
            if (ry < 0 || ry >= H || ly < 0 || ly > TH) continue;
            float wfy = 1.0f - fabsf(wy - (float)ry);
            #pragma unroll
            for (int dx = 0; dx < 2; ++dx) {
                int rx = fxi + dx, lx = rx - x0;
                if (rx < 0 || rx >= W || lx < 0 || lx > TW) continue;
                float wgt = wfy * (1.0f - fabsf(wx - (float)rx));
                int px = ly * (TW + 1) + lx;
                unsigned w18 = __float2uint_rn(wgt * PSCALE);
                unsigned s18 = __float2uint_rn(wgt * sw * PSCALE);
                atomicAdd(&sacc[f * TPX + px],
                          ((unsigned long long)w18 << 32) | s18);
            }
        }
    }
    __syncthreads();

    // Interior pixels finalize locally; tile-edge pixels (y%48==0 row-lines,
    // else x%64==0 col-lines) merge via global u64 atomics into line buffer.
    double l = 0.0, nz = 0.0;
    unsigned long long* bj = bnd + (size_t)(b * 2 + t) * BPX * 2;
    for (int p = tid; p < TPX; p += 256) {
        int ly = p / (TW + 1), lx = p - ly * (TW + 1);
        int y = y0 + ly, x = x0 + lx;
        if (y >= H || x >= W) continue;
        unsigned long long vp = sacc[p];
        unsigned long long vn = sacc[TPX + p];
        if (ly == 0 || ly == TH) {
            int off = (y / TH) * W + x;
            if (vp) atomicAdd(&bj[(size_t)off * 2], vp);
            if (vn) atomicAdd(&bj[(size_t)off * 2 + 1], vn);
        } else if (lx == 0 || lx == TW) {
            int off = TILES_Y * W + (x >> 6) * H + y;
            if (vp) atomicAdd(&bj[(size_t)off * 2], vp);
            if (vn) atomicAdd(&bj[(size_t)off * 2 + 1], vn);
        } else {
            float fwp = (float)(unsigned)(vp >> 32) * PINV;
            float fsp = (float)(unsigned)vp * PINV;
            float fwn = (float)(unsigned)(vn >> 32) * PINV;
            float fsn = (float)(unsigned)vn * PINV;
            float a = fsp / (fwp + EPS);
            float c = fsn / (fwn + EPS);
            l += (double)(a * a + c * c);
            if ((vp | vn) >> 32) nz += 1.0;
        }
    }
    double lt = blk_reduce(l, sm);
    double nt = blk_reduce(nz, sm);
    if (tid == 0) {
        int j = b * 2 + t;
        accL[j * TILES + tile] = lt;   // distinct slot: NO atomics
        accN[j * TILES + tile] = nt;
    }
}

// Reduce the line buffer. grid (44, 16). Col-line slots with y%48==0 are
// never written -> zero -> no double count.
__global__ __launch_bounds__(256) void bound_kernel(
    const unsigned long long* __restrict__ bnd,
    double* __restrict__ bndL, double* __restrict__ bndN) {
    __shared__ double sm[8];
    int j = blockIdx.y;
    double l = 0.0, nz = 0.0;
    for (int p = blockIdx.x * blockDim.x + threadIdx.x; p < BPX;
         p += gridDim.x * blockDim.x) {
        unsigned long long vp = bnd[((size_t)j * BPX + p) * 2];
        unsigned long long vn = bnd[((size_t)j * BPX + p) * 2 + 1];
        unsigned wp = (unsigned)(vp >> 32), sp = (unsigned)vp;
        unsigned wn = (unsigned)(vn >> 32), sn = (unsigned)vn;
        float a = ((float)sp * PINV) / ((float)wp * PINV + EPS);
        float c = ((float)sn * PINV) / ((float)wn * PINV + EPS);
        l += (double)(a * a + c * c);
        if (wp | wn) nz += 1.0;
    }
    double lt = blk_reduce(l, sm);
    double nt = blk_reduce(nz, sm);
    if (threadIdx.x == 0) {
        bndL[j * BND_BLK + blockIdx.x] = lt;
        bndN[j * BND_BLK + blockIdx.x] = nt;
    }
}

__device__ inline float charb(float a, float b) {
    return sqrtf(a * a + b * b + 1e-6f);
}

__global__ __launch_bounds__(256) void smooth_kernel(
    const float* __restrict__ flow, double* __restrict__ smP) {
    __shared__ double sm[8];
    double sdx = 0.0, sdy = 0.0, sdr = 0.0, sur = 0.0;
    int stride = gridDim.x * blockDim.x;
    for (int i = blockIdx.x * blockDim.x + threadIdx.x; i < B * HW; i += stride) {
        int b = i / HW;
        int rem = i - b * HW;
        int y = rem / W;
        int x = rem - y * W;
        const float* fx = flow + (size_t)(b * 2 + 0) * HW;
        const float* fy = flow + (size_t)(b * 2 + 1) * HW;
        float f00 = fx[rem], g00 = fy[rem];
        bool xe = (x + 1) < W;
        bool ye = (y + 1) < H;
        if (xe) {
            float f01 = fx[rem + 1], g01 = fy[rem + 1];
            sdx += (double)charb(f00 - f01, g00 - g01);
            if (ye) {
                float f10 = fx[rem + W], g10 = fy[rem + W];
                float f11 = fx[rem + W + 1], g11 = fy[rem + W + 1];
                sdy += (double)charb(f00 - f10, g00 - g10);
                sdr += (double)charb(f00 - f11, g00 - g11);
                sur += (double)charb(f10 - f01, g10 - g01);
            }
        } else if (ye) {
            float f10 = fx[rem + W], g10 = fy[rem + W];
            sdy += (double)charb(f00 - f10, g00 - g10);
        }
    }
    double tt;
    tt = blk_reduce(sdx, sm); if (threadIdx.x == 0) smP[blockIdx.x * 4 + 0] = tt;
    tt = blk_reduce(sdy, sm); if (threadIdx.x == 0) smP[blockIdx.x * 4 + 1] = tt;
    tt = blk_reduce(sdr, sm); if (threadIdx.x == 0) smP[blockIdx.x * 4 + 2] = tt;
    tt = blk_reduce(sur, sm); if (threadIdx.x == 0) smP[blockIdx.x * 4 + 3] = tt;
}

// One block, 256 threads. 16 threads per job reduce accL/accN + bndL/bndN
// (width-16 shfl); whole block reduces the 4 smooth components.
__global__ __launch_bounds__(256) void final_kernel(
    const double* __restrict__ accL, const double* __restrict__ accN,
    const double* __restrict__ bndL, const double* __restrict__ bndN,
    const double* __restrict__ smP, float* __restrict__ out) {
    __shared__ double sj[16];
    __shared__ double sm[8];
    int tid = threadIdx.x;
    int j = tid >> 4, s = tid & 15;
    double l = 0.0, nz = 0.0;
    for (int i = s; i < TILES; i += 16) {
        l += accL[j * TILES + i];
        nz += accN[j * TILES + i];
    }
    for (int i = s; i < BND_BLK; i += 16) {
        l += bndL[j * BND_BLK + i];
        nz += bndN[j * BND_BLK + i];
    }
    #pragma unroll
    for (int o = 8; o > 0; o >>= 1) {
        l += __shfl_down(l, o, 16);
        nz += __shfl_down(nz, o, 16);
    }
    if (s == 0) sj[j] = l / nz;

    double c[4] = {0.0, 0.0, 0.0, 0.0};
    for (int i = tid; i < SM_BLK; i += 256) {
        #pragma unroll
        for (int k = 0; k < 4; ++k) c[k] += smP[i * 4 + k];
    }
    double s0 = blk_reduce(c[0], sm);
    double s1 = blk_reduce(c[1], sm);
    double s2 = blk_reduce(c[2], sm);
    double s3 = blk_reduce(c[3], sm);
    __syncthreads();
    if (tid == 0) {
        double loss = 0.0;
        for (int q = 0; q < 16; ++q) loss += sj[q];
        double ndx = (double)B * H * (W - 1);
        double ndy = (double)B * (H - 1) * W;
        double ndd = (double)B * (H - 1) * (W - 1);
        double smooth = (s0 / ndx + s1 / ndy + s2 / ndd + s3 / ndd) * 0.25;
        out[0] = (float)(loss + 0.001 * smooth);
    }
}

extern "C" void kernel_launch(void* const* d_in, const int* in_sizes, int n_in,
                              void* d_out, int out_size, void* d_ws, size_t ws_size,
                              hipStream_t stream) {
    const float* flow = (const float*)d_in[0];
    const float* ts   = (const float*)d_in[1];
    const int*   ys   = (const int*)d_in[2];
    const int*   xs   = (const int*)d_in[3];
    const int*   pol  = (const int*)d_in[4];
    float* out = (float*)d_out;

    char* ws = (char*)d_ws;
    double* accL = (double*)(ws + ACCL_OFF);
    double* accN = (double*)(ws + ACCN_OFF);
    double* bndL = (double*)(ws + BNDL_OFF);
    double* bndN = (double*)(ws + BNDN_OFF);
    double* smP  = (double*)(ws + SMP_OFF);
    unsigned* cursors = (unsigned*)(ws + CUR_OFF);
    unsigned long long* bnd = (unsigned long long*)(ws + BND_OFF);
    unsigned long long* items = (unsigned long long*)(ws + ITEMS_OFF);

    // cursors + line buffer must start at zero (partial arrays are fully
    // written by their producers — no zeroing needed).
    hipMemsetAsync(ws + CUR_OFF, 0, ITEMS_OFF - CUR_OFF, stream);
    smooth_kernel<<<SM_BLK, 256, 0, stream>>>(flow, smP);
    scatter_kernel<<<SC_BLOCKS, 256, 0, stream>>>(flow, ts, ys, xs, pol, items, cursors);
    accum_kernel<<<NBINS, 256, 0, stream>>>(items, cursors, bnd, accL, accN);
    bound_kernel<<<dim3(BND_BLK, 16), 256, 0, stream>>>(bnd, bndL, bndN);
    final_kernel<<<1, 256, 0, stream>>>(accL, accN, bndL, bndN, smP, out);
}

// Round 6
// 154.231 us; speedup vs baseline: 7.5055x; 1.0308x over previous
//
#include <hip/hip_runtime.h>

// EventWarping: contrast-maximization loss for event-camera flow.
// flow [B,2,H,W] f32, ts [B,N,1] f32, ys/xs/pol [B,N] i32 -> scalar f32.
//
// Round 6: (a) accum's tile-edge flush (~0.5M global u64 atomics ~ 24Gop/s
// ceiling ~= 15-20us) replaced by per-tile private edge strips (plain
// coalesced stores); bound gathers the <=4 contributors per line pixel.
// (b) smooth fused into the scatter launch (block-range split) so its
// ~10us hides under scatter's latency-bound gathers. (c) memset now 6.4KB
// (cursors only). Harness's 256MiB ws poison (42us) is outside our control.

constexpr int H = 480, W = 640, HW = H * W;
constexpr int B = 8, N = 131072;
constexpr float FLOW_SCALING = 640.0f;
constexpr float EPS = 1e-9f;

constexpr int TH = 48, TW = 64;            // tile size
constexpr int TILES_Y = H / TH;            // 10
constexpr int TILES_X = W / TW;            // 10
constexpr int TILES = TILES_Y * TILES_X;   // 100
constexpr int NBINS = B * 2 * TILES;       // 1600 (b, tref, tile)
constexpr int CAP = 4096;                  // slots per bin (mean ~1310, 77 sigma)

constexpr float PSCALE = 262144.0f;        // 2^18 fixed point
constexpr float PINV = 1.0f / 262144.0f;

constexpr int BND_BLK = 44;                // bound grid.x
constexpr int SM_BLK = 512;                // smooth block count (fused)
constexpr int SC_BLOCKS = 1024;            // scatter block count (fused)

// Per-tile edge strip: seg0 ly=0 (65), seg1 ly=TH (65), seg2 lx=0,ly=1..47
// (47), seg3 lx=TW,ly=1..47 (47) => 224 entries x {pos,neg} u64.
constexpr int EDGE_PX = 224;

// Line-pixel index space per job: row-lines k*W+x (6400), col-lines
// 6400 + m*H + y (4800). Col entries with y%48==0 are owned by row-lines.
constexpr int BPX = TILES_Y * W + TILES_X * H;   // 11200

// Workspace layout:
constexpr size_t ACCL_OFF = 0;                                        // f64[16][100]
constexpr size_t ACCN_OFF = ACCL_OFF + (size_t)16 * TILES * 8;        // 12800
constexpr size_t BNDL_OFF = ACCN_OFF + (size_t)16 * TILES * 8;        // 25600
constexpr size_t BNDN_OFF = BNDL_OFF + (size_t)16 * BND_BLK * 8;      // 31232
constexpr size_t SMP_OFF  = BNDN_OFF + (size_t)16 * BND_BLK * 8;      // 36864
constexpr size_t CUR_OFF  = SMP_OFF + (size_t)SM_BLK * 4 * 8;         // 53248
constexpr size_t BNDE_OFF = CUR_OFF + (size_t)NBINS * 4;              // 59648
constexpr size_t BNDE_BYTES = (size_t)NBINS * EDGE_PX * 2 * 8;        // 5734400
constexpr size_t ITEMS_OFF = BNDE_OFF + BNDE_BYTES;

__device__ inline double blk_reduce(double v, double* sm) {
    __syncthreads();
    #pragma unroll
    for (int o = 32; o > 0; o >>= 1) v += __shfl_down(v, o, 64);
    int lane = threadIdx.x & 63;
    int wid  = threadIdx.x >> 6;
    if (lane == 0) sm[wid] = v;
    __syncthreads();
    double r = 0.0;
    if (threadIdx.x == 0) {
        int nw = (int)(blockDim.x >> 6);
        for (int w2 = 0; w2 < nw; ++w2) r += sm[w2];
    }
    return r;  // thread 0 only
}

// Local bin id (tref*100 + tile) from the PACKED payload, so count and
// placement phases can never disagree.
__device__ inline int bin_from_payload(unsigned long long v) {
    int t = (int)(v & 1);
    int fyi = (int)((unsigned)(v >> 40) >> 12) - 512;
    int fxi = (int)(((unsigned)(v >> 16) & 0xFFFFFFu) >> 12) - 512;
    int cy = min(max(fyi, 0), H - 1);
    int cx = min(max(fxi, 0), W - 1);
    return t * TILES + (cy / TH) * TILES_X + (cx >> 6);
}

__device__ inline float charb(float a, float b) {
    return sqrtf(a * a + b * b + 1e-6f);
}

// Fused: blocks [0, SC_BLOCKS) scatter events; [SC_BLOCKS, +SM_BLK) smooth.
// Scatter: batch = blockIdx&7 (XCD pin), 1024 events/block, payloads in
// registers. Payload u64: [63:40] (wy+512)*4096 rn, [39:16] (wx+512)*4096,
// [15:2] sw*16383 rn, [1] pol, [0] tref.
__global__ __launch_bounds__(256) void scatter_smooth_kernel(
    const float* __restrict__ flow, const float* __restrict__ ts,
    const int* __restrict__ ys, const int* __restrict__ xs,
    const int* __restrict__ pol,
    unsigned long long* __restrict__ items, unsigned* __restrict__ cursors,
    double* __restrict__ smP) {
    __shared__ unsigned scount[200];
    __shared__ unsigned sbase[200];
    __shared__ unsigned scur[200];
    __shared__ double sm[8];
    int tid = threadIdx.x;

    if (blockIdx.x >= SC_BLOCKS) {
        // ---- smooth path ----
        int sb = blockIdx.x - SC_BLOCKS;
        double sdx = 0.0, sdy = 0.0, sdr = 0.0, sur = 0.0;
        int stride = SM_BLK * 256;
        for (int i = sb * 256 + tid; i < B * HW; i += stride) {
            int b = i / HW;
            int rem = i - b * HW;
            int y = rem / W;
            int x = rem - y * W;
            const float* fx = flow + (size_t)(b * 2 + 0) * HW;
            const float* fy = flow + (size_t)(b * 2 + 1) * HW;
            float f00 = fx[rem], g00 = fy[rem];
            bool xe = (x + 1) < W;
            bool ye = (y + 1) < H;
            if (xe) {
                float f01 = fx[rem + 1], g01 = fy[rem + 1];
                sdx += (double)charb(f00 - f01, g00 - g01);
                if (ye) {
                    float f10 = fx[rem + W], g10 = fy[rem + W];
                    float f11 = fx[rem + W + 1], g11 = fy[rem + W + 1];
                    sdy += (double)charb(f00 - f10, g00 - g10);
                    sdr += (double)charb(f00 - f11, g00 - g11);
                    sur += (double)charb(f10 - f01, g10 - g01);
                }
            } else if (ye) {
                float f10 = fx[rem + W], g10 = fy[rem + W];
                sdy += (double)charb(f00 - f10, g00 - g10);
            }
        }
        double tt;
        tt = blk_reduce(sdx, sm); if (tid == 0) smP[sb * 4 + 0] = tt;
        tt = blk_reduce(sdy, sm); if (tid == 0) smP[sb * 4 + 1] = tt;
        tt = blk_reduce(sdr, sm); if (tid == 0) smP[sb * 4 + 2] = tt;
        tt = blk_reduce(sur, sm); if (tid == 0) smP[sb * 4 + 3] = tt;
        return;
    }

    // ---- scatter path ----
    if (tid < 200) { scount[tid] = 0; scur[tid] = 0; }
    __syncthreads();

    int b = blockIdx.x & 7;
    int chunk = blockIdx.x >> 3;          // 0..127
    int e0 = b * N + chunk * 1024;
    const float* fb = flow + (size_t)b * 2 * HW;

    unsigned long long pay[8];
    #pragma unroll
    for (int k = 0; k < 4; ++k) {
        int e = e0 + k * 256 + tid;
        int y = ys[e], x = xs[e], p = pol[e];
        float t0 = ts[e];
        int flat = y * W + x;
        float fx = fb[flat];
        float fy = fb[HW + flat];
        #pragma unroll
        for (int t = 0; t < 2; ++t) {
            float dt = (t == 0 ? 1.0f : 0.0f) - t0;
            float sw = (t == 0) ? t0 : 1.0f - t0;
            float wy = (float)y + dt * fy * FLOW_SCALING;
            float wx = (float)x + dt * fx * FLOW_SCALING;
            unsigned long long v = ~0ull;  // sentinel = invalid
            if (wy >= -1.0f && wy < (float)H && wx >= -1.0f && wx < (float)W) {
                unsigned uy = __float2uint_rn((wy + 512.0f) * 4096.0f);
                unsigned ux = __float2uint_rn((wx + 512.0f) * 4096.0f);
                unsigned usw = __float2uint_rn(sw * 16383.0f);
                v = ((unsigned long long)uy << 40) |
                    ((unsigned long long)ux << 16) |
                    ((unsigned long long)usw << 2) |
                    ((unsigned long long)(p != 0) << 1) |
                    (unsigned long long)t;
                atomicAdd(&scount[bin_from_payload(v)], 1u);
            }
            pay[k * 2 + t] = v;
        }
    }
    __syncthreads();
    if (tid < 200) {
        unsigned c = scount[tid];
        sbase[tid] = c ? atomicAdd(&cursors[b * 200 + tid], c) : 0u;
    }
    __syncthreads();
    #pragma unroll
    for (int i = 0; i < 8; ++i) {
        unsigned long long v = pay[i];
        if (v == ~0ull) continue;
        int binl = bin_from_payload(v);
        unsigned idx = sbase[binl] + atomicAdd(&scur[binl], 1u);
        if (idx < (unsigned)CAP)
            items[(size_t)(b * 200 + binl) * CAP + idx] = v;
    }
}

// One block per bin (b,t,tile). LDS tile 49x65, u64 per pixel per polarity
// field (0=pos, 1=neg), packing (w<<32 | s) at 2^18 fixed point.
// Interior pixels finalize in-LDS; edge pixels stored (NO atomics) to the
// tile's private strip in bndE; bound gathers.
__global__ __launch_bounds__(256) void accum_kernel(
    const unsigned long long* __restrict__ items,
    const unsigned* __restrict__ cursors,
    unsigned long long* __restrict__ bndE,
    double* __restrict__ accL, double* __restrict__ accN) {
    constexpr int TPX = (TH + 1) * (TW + 1);      // 3185
    __shared__ unsigned long long sacc[2 * TPX];  // 50,960 B
    __shared__ double sm[8];
    int tid = threadIdx.x;
    for (int i = tid; i < 2 * TPX; i += 256) sacc[i] = 0ull;
    __syncthreads();

    int bin = blockIdx.x;
    int b = bin / 200;
    int loc = bin - b * 200;
    int t = loc / TILES;
    int tile = loc - t * TILES;
    int y0 = (tile / TILES_X) * TH;
    int x0 = (tile % TILES_X) * TW;
    int cnt = (int)min(cursors[bin], (unsigned)CAP);
    const unsigned long long* bi = items + (size_t)bin * CAP;

    for (int i = tid; i < cnt; i += 256) {
        unsigned long long v = bi[i];
        unsigned uy = (unsigned)(v >> 40);
        unsigned ux = (unsigned)(v >> 16) & 0xFFFFFFu;
        float wy = (float)uy * (1.0f / 4096.0f) - 512.0f;
        float wx = (float)ux * (1.0f / 4096.0f) - 512.0f;
        int fyi = (int)(uy >> 12) - 512;
        int fxi = (int)(ux >> 12) - 512;
        float sw = (float)((unsigned)(v >> 2) & 0x3FFFu) * (1.0f / 16383.0f);
        int f = ((v >> 1) & 1) ? 0 : 1;  // pol=1 -> pos field
        #pragma unroll
        for (int dy = 0; dy < 2; ++dy) {
            int ry = fyi + dy, ly = ry - y0;
            if (ry < 0 || ry >= H || ly < 0 || ly > TH) continue;
            float wfy = 1.0f - fabsf(wy - (float)ry);
            #pragma unroll
            for (int dx = 0; dx < 2; ++dx) {
                int rx = fxi + dx, lx = rx - x0;
                if (rx < 0 || rx >= W || lx < 0 || lx > TW) continue;
                float wgt = wfy * (1.0f - fabsf(wx - (float)rx));
                int px = ly * (TW + 1) + lx;
                unsigned w18 = __float2uint_rn(wgt * PSCALE);
                unsigned s18 = __float2uint_rn(wgt * sw * PSCALE);
                atomicAdd(&sacc[f * TPX + px],
                          ((unsigned long long)w18 << 32) | s18);
            }
        }
    }
    __syncthreads();

    double l = 0.0, nz = 0.0;
    unsigned long long* eb = bndE + (size_t)bin * EDGE_PX * 2;
    for (int p = tid; p < TPX; p += 256) {
        int ly = p / (TW + 1), lx = p - ly * (TW + 1);
        unsigned long long vp = sacc[p];
        unsigned long long vn = sacc[TPX + p];
        // Edge classification (priority: rows own corners).
        int slot = -1;
        if (ly == 0)           slot = lx;               // seg0
        else if (ly == TH)     slot = 65 + lx;          // seg1
        else if (lx == 0)      slot = 130 + (ly - 1);   // seg2
        else if (lx == TW)     slot = 177 + (ly - 1);   // seg3
        if (slot >= 0) {
            eb[(size_t)slot * 2]     = vp;   // unconditional: buffer unzeroed
            eb[(size_t)slot * 2 + 1] = vn;
        } else {
            float fwp = (float)(unsigned)(vp >> 32) * PINV;
            float fsp = (float)(unsigned)vp * PINV;
            float fwn = (float)(unsigned)(vn >> 32) * PINV;
            float fsn = (float)(unsigned)vn * PINV;
            float a = fsp / (fwp + EPS);
            float c = fsn / (fwn + EPS);
            l += (double)(a * a + c * c);
            if ((vp | vn) >> 32) nz += 1.0;
        }
    }
    double lt = blk_reduce(l, sm);
    double nt = blk_reduce(nz, sm);
    if (tid == 0) {
        int j = b * 2 + t;
        accL[j * TILES + tile] = lt;   // distinct slot: NO atomics
        accN[j * TILES + tile] = nt;
    }
}

// Gather-reduce the line pixels. grid (44, 16). Row-lines own corners; col
// entries with y%48==0 contribute zero (counted by their row-line entry).
__global__ __launch_bounds__(256) void bound_kernel(
    const unsigned long long* __restrict__ bndE,
    double* __restrict__ bndL, double* __restrict__ bndN) {
    __shared__ double sm[8];
    int j = blockIdx.y;
    int b = j >> 1, t = j & 1;
    const unsigned long long* jb =
        bndE + (size_t)(b * 200 + t * 100) * EDGE_PX * 2;

    double l = 0.0, nz = 0.0;
    for (int p = blockIdx.x * blockDim.x + threadIdx.x; p < BPX;
         p += gridDim.x * blockDim.x) {
        unsigned long long vp = 0ull, vn = 0ull;
        if (p < TILES_Y * W) {
            int k = p / W, x = p - k * W;
            int m = x >> 6, lx = x & 63;
            const unsigned long long* e;
            e = jb + ((size_t)(k * TILES_X + m) * EDGE_PX + lx) * 2;      // seg0
            vp += e[0]; vn += e[1];
            if (k > 0) {
                e = jb + ((size_t)((k - 1) * TILES_X + m) * EDGE_PX + 65 + lx) * 2;
                vp += e[0]; vn += e[1];
            }
            if (lx == 0 && m > 0) {
                e = jb + ((size_t)(k * TILES_X + m - 1) * EDGE_PX + 64) * 2;
                vp += e[0]; vn += e[1];
                if (k > 0) {
                    e = jb + ((size_t)((k - 1) * TILES_X + m - 1) * EDGE_PX + 129) * 2;
                    vp += e[0]; vn += e[1];
                }
            }
        } else {
            int q = p - TILES_Y * W;
            int m = q / H, y = q - m * H;
            int r = y / TH, ly = y - r * TH;
            if (ly != 0) {
                const unsigned long long* e;
                e = jb + ((size_t)(r * TILES_X + m) * EDGE_PX + 130 + ly - 1) * 2;
                vp += e[0]; vn += e[1];
                if (m > 0) {
                    e = jb + ((size_t)(r * TILES_X + m - 1) * EDGE_PX + 177 + ly - 1) * 2;
                    vp += e[0]; vn += e[1];
                }
            }
        }
        unsigned wp = (unsigned)(vp >> 32), sp = (unsigned)vp;
        unsigned wn = (unsigned)(vn >> 32), sn = (unsigned)vn;
        float a = ((float)sp * PINV) / ((float)wp * PINV + EPS);
        float c = ((float)sn * PINV) / ((float)wn * PINV + EPS);
        l += (double)(a * a + c * c);
        if (wp | wn) nz += 1.0;
    }
    double lt = blk_reduce(l, sm);
    double nt = blk_reduce(nz, sm);
    if (threadIdx.x == 0) {
        bndL[j * BND_BLK + blockIdx.x] = lt;
        bndN[j * BND_BLK + blockIdx.x] = nt;
    }
}

// One block, 256 threads: 16 threads per job reduce accL/N + bndL/N
// (width-16 shfl); whole block reduces the 4 smooth sums.
__global__ __launch_bounds__(256) void final_kernel(
    const double* __restrict__ accL, const double* __restrict__ accN,
    const double* __restrict__ bndL, const double* __restrict__ bndN,
    const double* __restrict__ smP, float* __restrict__ out) {
    __shared__ double sj[16];
    __shared__ double sm[8];
    int tid = threadIdx.x;
    int j = tid >> 4, s = tid & 15;
    double l = 0.0, nz = 0.0;
    for (int i = s; i < TILES; i += 16) {
        l += accL[j * TILES + i];
        nz += accN[j * TILES + i];
    }
    for (int i = s; i < BND_BLK; i += 16) {
        l += bndL[j * BND_BLK + i];
        nz += bndN[j * BND_BLK + i];
    }
    #pragma unroll
    for (int o = 8; o > 0; o >>= 1) {
        l += __shfl_down(l, o, 16);
        nz += __shfl_down(nz, o, 16);
    }
    if (s == 0) sj[j] = l / nz;

    double c[4] = {0.0, 0.0, 0.0, 0.0};
    for (int i = tid; i < SM_BLK; i += 256) {
        #pragma unroll
        for (int k = 0; k < 4; ++k) c[k] += smP[i * 4 + k];
    }
    double s0 = blk_reduce(c[0], sm);
    double s1 = blk_reduce(c[1], sm);
    double s2 = blk_reduce(c[2], sm);
    double s3 = blk_reduce(c[3], sm);
    __syncthreads();
    if (tid == 0) {
        double loss = 0.0;
        for (int q = 0; q < 16; ++q) loss += sj[q];
        double ndx = (double)B * H * (W - 1);
        double ndy = (double)B * (H - 1) * W;
        double ndd = (double)B * (H - 1) * (W - 1);
        double smooth = (s0 / ndx + s1 / ndy + s2 / ndd + s3 / ndd) * 0.25;
        out[0] = (float)(loss + 0.001 * smooth);
    }
}

extern "C" void kernel_launch(void* const* d_in, const int* in_sizes, int n_in,
                              void* d_out, int out_size, void* d_ws, size_t ws_size,
                              hipStream_t stream) {
    const float* flow = (const float*)d_in[0];
    const float* ts   = (const float*)d_in[1];
    const int*   ys   = (const int*)d_in[2];
    const int*   xs   = (const int*)d_in[3];
    const int*   pol  = (const int*)d_in[4];
    float* out = (float*)d_out;

    char* ws = (char*)d_ws;
    double* accL = (double*)(ws + ACCL_OFF);
    double* accN = (double*)(ws + ACCN_OFF);
    double* bndL = (double*)(ws + BNDL_OFF);
    double* bndN = (double*)(ws + BNDN_OFF);
    double* smP  = (double*)(ws + SMP_OFF);
    unsigned* cursors = (unsigned*)(ws + CUR_OFF);
    unsigned long long* bndE = (unsigned long long*)(ws + BNDE_OFF);
    unsigned long long* items = (unsigned long long*)(ws + ITEMS_OFF);

    // Only cursors need zeroing (everything else is fully written by its
    // producer before being read).
    hipMemsetAsync(cursors, 0, (size_t)NBINS * 4, stream);
    scatter_smooth_kernel<<<SC_BLOCKS + SM_BLK, 256, 0, stream>>>(
        flow, ts, ys, xs, pol, items, cursors, smP);
    accum_kernel<<<NBINS, 256, 0, stream>>>(items, cursors, bndE, accL, accN);
    bound_kernel<<<dim3(BND_BLK, 16), 256, 0, stream>>>(bndE, bndL, bndN);
    final_kernel<<<1, 256, 0, stream>>>(accL, accN, bndL, bndN, smP, out);
}

// Round 7
// 150.035 us; speedup vs baseline: 7.7154x; 1.0280x over previous
//
#include <hip/hip_runtime.h>

// EventWarping: contrast-maximization loss for event-camera flow.
// flow [B,2,H,W] f32, ts [B,N,1] f32, ys/xs/pol [B,N] i32 -> scalar f32.
//
// Round 7: scatter_smooth was latency-bound (45us, FETCH=input-exact 38MB,
// HBM 15%, occ 37%):
//  (a) smooth blocks now FIRST in the fused launch (they stream; scatter's
//      latency-bound blocks fill in behind) -> no serialized smooth tail;
//  (b) scatter preloads 4 event records then issues all 8 random flow
//      gathers back-to-back (8 outstanding loads/thread vs 2) before
//      computing payloads -> 4x memory-level parallelism on the L2 gathers.
// Everything downstream unchanged from round 6.

constexpr int H = 480, W = 640, HW = H * W;
constexpr int B = 8, N = 131072;
constexpr float FLOW_SCALING = 640.0f;
constexpr float EPS = 1e-9f;

constexpr int TH = 48, TW = 64;            // tile size
constexpr int TILES_Y = H / TH;            // 10
constexpr int TILES_X = W / TW;            // 10
constexpr int TILES = TILES_Y * TILES_X;   // 100
constexpr int NBINS = B * 2 * TILES;       // 1600 (b, tref, tile)
constexpr int CAP = 4096;                  // slots per bin (mean ~1310, 77 sigma)

constexpr float PSCALE = 262144.0f;        // 2^18 fixed point
constexpr float PINV = 1.0f / 262144.0f;

constexpr int BND_BLK = 44;                // bound grid.x
constexpr int SM_BLK = 512;                // smooth block count (fused, first)
constexpr int SC_BLOCKS = 1024;            // scatter block count (fused)

// Per-tile edge strip: seg0 ly=0 (65), seg1 ly=TH (65), seg2 lx=0,ly=1..47
// (47), seg3 lx=TW,ly=1..47 (47) => 224 entries x {pos,neg} u64.
constexpr int EDGE_PX = 224;

// Line-pixel index space per job: row-lines k*W+x (6400), col-lines
// 6400 + m*H + y (4800). Col entries with y%48==0 are owned by row-lines.
constexpr int BPX = TILES_Y * W + TILES_X * H;   // 11200

// Workspace layout:
constexpr size_t ACCL_OFF = 0;                                        // f64[16][100]
constexpr size_t ACCN_OFF = ACCL_OFF + (size_t)16 * TILES * 8;        // 12800
constexpr size_t BNDL_OFF = ACCN_OFF + (size_t)16 * TILES * 8;        // 25600
constexpr size_t BNDN_OFF = BNDL_OFF + (size_t)16 * BND_BLK * 8;      // 31232
constexpr size_t SMP_OFF  = BNDN_OFF + (size_t)16 * BND_BLK * 8;      // 36864
constexpr size_t CUR_OFF  = SMP_OFF + (size_t)SM_BLK * 4 * 8;         // 53248
constexpr size_t BNDE_OFF = CUR_OFF + (size_t)NBINS * 4;              // 59648
constexpr size_t BNDE_BYTES = (size_t)NBINS * EDGE_PX * 2 * 8;        // 5734400
constexpr size_t ITEMS_OFF = BNDE_OFF + BNDE_BYTES;

__device__ inline double blk_reduce(double v, double* sm) {
    __syncthreads();
    #pragma unroll
    for (int o = 32; o > 0; o >>= 1) v += __shfl_down(v, o, 64);
    int lane = threadIdx.x & 63;
    int wid  = threadIdx.x >> 6;
    if (lane == 0) sm[wid] = v;
    __syncthreads();
    double r = 0.0;
    if (threadIdx.x == 0) {
        int nw = (int)(blockDim.x >> 6);
        for (int w2 = 0; w2 < nw; ++w2) r += sm[w2];
    }
    return r;  // thread 0 only
}

// Local bin id (tref*100 + tile) from the PACKED payload, so count and
// placement phases can never disagree.
__device__ inline int bin_from_payload(unsigned long long v) {
    int t = (int)(v & 1);
    int fyi = (int)((unsigned)(v >> 40) >> 12) - 512;
    int fxi = (int)(((unsigned)(v >> 16) & 0xFFFFFFu) >> 12) - 512;
    int cy = min(max(fyi, 0), H - 1);
    int cx = min(max(fxi, 0), W - 1);
    return t * TILES + (cy / TH) * TILES_X + (cx >> 6);
}

__device__ inline float charb(float a, float b) {
    return sqrtf(a * a + b * b + 1e-6f);
}

// Fused: blocks [0, SM_BLK) smooth; [SM_BLK, SM_BLK+SC_BLOCKS) scatter.
// Scatter: batch = sc&7 (XCD pin; SM_BLK%8==0 preserves the mapping),
// 1024 events/block, payloads in registers. Payload u64:
// [63:40] (wy+512)*4096 rn, [39:16] (wx+512)*4096 rn, [15:2] sw*16383 rn,
// [1] pol, [0] tref.
__global__ __launch_bounds__(256) void scatter_smooth_kernel(
    const float* __restrict__ flow, const float* __restrict__ ts,
    const int* __restrict__ ys, const int* __restrict__ xs,
    const int* __restrict__ pol,
    unsigned long long* __restrict__ items, unsigned* __restrict__ cursors,
    double* __restrict__ smP) {
    __shared__ unsigned scount[200];
    __shared__ unsigned sbase[200];
    __shared__ unsigned scur[200];
    __shared__ double sm[8];
    int tid = threadIdx.x;

    if (blockIdx.x < SM_BLK) {
        // ---- smooth path (first: streams at full BW while scatter fills) ----
        int sb = blockIdx.x;
        double sdx = 0.0, sdy = 0.0, sdr = 0.0, sur = 0.0;
        int stride = SM_BLK * 256;
        for (int i = sb * 256 + tid; i < B * HW; i += stride) {
            int b = i / HW;
            int rem = i - b * HW;
            int y = rem / W;
            int x = rem - y * W;
            const float* fx = flow + (size_t)(b * 2 + 0) * HW;
            const float* fy = flow + (size_t)(b * 2 + 1) * HW;
            float f00 = fx[rem], g00 = fy[rem];
            bool xe = (x + 1) < W;
            bool ye = (y + 1) < H;
            if (xe) {
                float f01 = fx[rem + 1], g01 = fy[rem + 1];
                sdx += (double)charb(f00 - f01, g00 - g01);
                if (ye) {
                    float f10 = fx[rem + W], g10 = fy[rem + W];
                    float f11 = fx[rem + W + 1], g11 = fy[rem + W + 1];
                    sdy += (double)charb(f00 - f10, g00 - g10);
                    sdr += (double)charb(f00 - f11, g00 - g11);
                    sur += (double)charb(f10 - f01, g10 - g01);
                }
            } else if (ye) {
                float f10 = fx[rem + W], g10 = fy[rem + W];
                sdy += (double)charb(f00 - f10, g00 - g10);
            }
        }
        double tt;
        tt = blk_reduce(sdx, sm); if (tid == 0) smP[sb * 4 + 0] = tt;
        tt = blk_reduce(sdy, sm); if (tid == 0) smP[sb * 4 + 1] = tt;
        tt = blk_reduce(sdr, sm); if (tid == 0) smP[sb * 4 + 2] = tt;
        tt = blk_reduce(sur, sm); if (tid == 0) smP[sb * 4 + 3] = tt;
        return;
    }

    // ---- scatter path ----
    if (tid < 200) { scount[tid] = 0; scur[tid] = 0; }
    __syncthreads();

    int sc = blockIdx.x - SM_BLK;
    int b = sc & 7;
    int chunk = sc >> 3;                  // 0..127
    int e0 = b * N + chunk * 1024;
    const float* fb = flow + (size_t)b * 2 * HW;

    // Phase 0: preload 4 event records (coalesced), then issue all 8 random
    // flow gathers back-to-back for max memory-level parallelism.
    int y4[4], x4[4], p4[4];
    float t4[4];
    #pragma unroll
    for (int k = 0; k < 4; ++k) {
        int e = e0 + k * 256 + tid;
        y4[k] = ys[e];
        x4[k] = xs[e];
        p4[k] = pol[e];
        t4[k] = ts[e];
    }
    float fx4[4], fy4[4];
    #pragma unroll
    for (int k = 0; k < 4; ++k) {
        int flat = y4[k] * W + x4[k];
        fx4[k] = fb[flat];
        fy4[k] = fb[HW + flat];
    }

    unsigned long long pay[8];
    #pragma unroll
    for (int k = 0; k < 4; ++k) {
        float t0 = t4[k];
        #pragma unroll
        for (int t = 0; t < 2; ++t) {
            float dt = (t == 0 ? 1.0f : 0.0f) - t0;
            float sw = (t == 0) ? t0 : 1.0f - t0;
            float wy = (float)y4[k] + dt * fy4[k] * FLOW_SCALING;
            float wx = (float)x4[k] + dt * fx4[k] * FLOW_SCALING;
            unsigned long long v = ~0ull;  // sentinel = invalid
            if (wy >= -1.0f && wy < (float)H && wx >= -1.0f && wx < (float)W) {
                unsigned uy = __float2uint_rn((wy + 512.0f) * 4096.0f);
                unsigned ux = __float2uint_rn((wx + 512.0f) * 4096.0f);
                unsigned usw = __float2uint_rn(sw * 16383.0f);
                v = ((unsigned long long)uy << 40) |
                    ((unsigned long long)ux << 16) |
                    ((unsigned long long)usw << 2) |
                    ((unsigned long long)(p4[k] != 0) << 1) |
                    (unsigned long long)t;
                atomicAdd(&scount[bin_from_payload(v)], 1u);
            }
            pay[k * 2 + t] = v;
        }
    }
    __syncthreads();
    if (tid < 200) {
        unsigned c = scount[tid];
        sbase[tid] = c ? atomicAdd(&cursors[b * 200 + tid], c) : 0u;
    }
    __syncthreads();
    #pragma unroll
    for (int i = 0; i < 8; ++i) {
        unsigned long long v = pay[i];
        if (v == ~0ull) continue;
        int binl = bin_from_payload(v);
        unsigned idx = sbase[binl] + atomicAdd(&scur[binl], 1u);
        if (idx < (unsigned)CAP)
            items[(size_t)(b * 200 + binl) * CAP + idx] = v;
    }
}

// One block per bin (b,t,tile). LDS tile 49x65, u64 per pixel per polarity
// field (0=pos, 1=neg), packing (w<<32 | s) at 2^18 fixed point.
// Interior pixels finalize in-LDS; edge pixels stored (NO atomics) to the
// tile's private strip in bndE; bound gathers.
__global__ __launch_bounds__(256) void accum_kernel(
    const unsigned long long* __restrict__ items,
    const unsigned* __restrict__ cursors,
    unsigned long long* __restrict__ bndE,
    double* __restrict__ accL, double* __restrict__ accN) {
    constexpr int TPX = (TH + 1) * (TW + 1);      // 3185
    __shared__ unsigned long long sacc[2 * TPX];  // 50,960 B
    __shared__ double sm[8];
    int tid = threadIdx.x;
    for (int i = tid; i < 2 * TPX; i += 256) sacc[i] = 0ull;
    __syncthreads();

    int bin = blockIdx.x;
    int b = bin / 200;
    int loc = bin - b * 200;
    int t = loc / TILES;
    int tile = loc - t * TILES;
    int y0 = (tile / TILES_X) * TH;
    int x0 = (tile % TILES_X) * TW;
    int cnt = (int)min(cursors[bin], (unsigned)CAP);
    const unsigned long long* bi = items + (size_t)bin * CAP;

    for (int i = tid; i < cnt; i += 256) {
        unsigned long long v = bi[i];
        unsigned uy = (unsigned)(v >> 40);
        unsigned ux = (unsigned)(v >> 16) & 0xFFFFFFu;
        float wy = (float)uy * (1.0f / 4096.0f) - 512.0f;
        float wx = (float)ux * (1.0f / 4096.0f) - 512.0f;
        int fyi = (int)(uy >> 12) - 512;
        int fxi = (int)(ux >> 12) - 512;
        float sw = (float)((unsigned)(v >> 2) & 0x3FFFu) * (1.0f / 16383.0f);
        int f = ((v >> 1) & 1) ? 0 : 1;  // pol=1 -> pos field
        #pragma unroll
        for (int dy = 0; dy < 2; ++dy) {
            int ry = fyi + dy, ly = ry - y0;
            if (ry < 0 || ry >= H || ly < 0 || ly > TH) continue;
            float wfy = 1.0f - fabsf(wy - (float)ry);
            #pragma unroll
            for (int dx = 0; dx < 2; ++dx) {
                int rx = fxi + dx, lx = rx - x0;
                if (rx < 0 || rx >= W || lx < 0 || lx > TW) continue;
                float wgt = wfy * (1.0f - fabsf(wx - (float)rx));
                int px = ly * (TW + 1) + lx;
                unsigned w18 = __float2uint_rn(wgt * PSCALE);
                unsigned s18 = __float2uint_rn(wgt * sw * PSCALE);
                atomicAdd(&sacc[f * TPX + px],
                          ((unsigned long long)w18 << 32) | s18);
            }
        }
    }
    __syncthreads();

    double l = 0.0, nz = 0.0;
    unsigned long long* eb = bndE + (size_t)bin * EDGE_PX * 2;
    for (int p = tid; p < TPX; p += 256) {
        int ly = p / (TW + 1), lx = p - ly * (TW + 1);
        unsigned long long vp = sacc[p];
        unsigned long long vn = sacc[TPX + p];
        // Edge classification (priority: rows own corners).
        int slot = -1;
        if (ly == 0)           slot = lx;               // seg0
        else if (ly == TH)     slot = 65 + lx;          // seg1
        else if (lx == 0)      slot = 130 + (ly - 1);   // seg2
        else if (lx == TW)     slot = 177 + (ly - 1);   // seg3
        if (slot >= 0) {
            eb[(size_t)slot * 2]     = vp;   // unconditional: buffer unzeroed
            eb[(size_t)slot * 2 + 1] = vn;
        } else {
            float fwp = (float)(unsigned)(vp >> 32) * PINV;
            float fsp = (float)(unsigned)vp * PINV;
            float fwn = (float)(unsigned)(vn >> 32) * PINV;
            float fsn = (float)(unsigned)vn * PINV;
            float a = fsp / (fwp + EPS);
            float c = fsn / (fwn + EPS);
            l += (double)(a * a + c * c);
            if ((vp | vn) >> 32) nz += 1.0;
        }
    }
    double lt = blk_reduce(l, sm);
    double nt = blk_reduce(nz, sm);
    if (tid == 0) {
        int j = b * 2 + t;
        accL[j * TILES + tile] = lt;   // distinct slot: NO atomics
        accN[j * TILES + tile] = nt;
    }
}

// Gather-reduce the line pixels. grid (44, 16). Row-lines own corners; col
// entries with y%48==0 contribute zero (counted by their row-line entry).
__global__ __launch_bounds__(256) void bound_kernel(
    const unsigned long long* __restrict__ bndE,
    double* __restrict__ bndL, double* __restrict__ bndN) {
    __shared__ double sm[8];
    int j = blockIdx.y;
    int b = j >> 1, t = j & 1;
    const unsigned long long* jb =
        bndE + (size_t)(b * 200 + t * 100) * EDGE_PX * 2;

    double l = 0.0, nz = 0.0;
    for (int p = blockIdx.x * blockDim.x + threadIdx.x; p < BPX;
         p += gridDim.x * blockDim.x) {
        unsigned long long vp = 0ull, vn = 0ull;
        if (p < TILES_Y * W) {
            int k = p / W, x = p - k * W;
            int m = x >> 6, lx = x & 63;
            const unsigned long long* e;
            e = jb + ((size_t)(k * TILES_X + m) * EDGE_PX + lx) * 2;      // seg0
            vp += e[0]; vn += e[1];
            if (k > 0) {
                e = jb + ((size_t)((k - 1) * TILES_X + m) * EDGE_PX + 65 + lx) * 2;
                vp += e[0]; vn += e[1];
            }
            if (lx == 0 && m > 0) {
                e = jb + ((size_t)(k * TILES_X + m - 1) * EDGE_PX + 64) * 2;
                vp += e[0]; vn += e[1];
                if (k > 0) {
                    e = jb + ((size_t)((k - 1) * TILES_X + m - 1) * EDGE_PX + 129) * 2;
                    vp += e[0]; vn += e[1];
                }
            }
        } else {
            int q = p - TILES_Y * W;
            int m = q / H, y = q - m * H;
            int r = y / TH, ly = y - r * TH;
            if (ly != 0) {
                const unsigned long long* e;
                e = jb + ((size_t)(r * TILES_X + m) * EDGE_PX + 130 + ly - 1) * 2;
                vp += e[0]; vn += e[1];
                if (m > 0) {
                    e = jb + ((size_t)(r * TILES_X + m - 1) * EDGE_PX + 177 + ly - 1) * 2;
                    vp += e[0]; vn += e[1];
                }
            }
        }
        unsigned wp = (unsigned)(vp >> 32), sp = (unsigned)vp;
        unsigned wn = (unsigned)(vn >> 32), sn = (unsigned)vn;
        float a = ((float)sp * PINV) / ((float)wp * PINV + EPS);
        float c = ((float)sn * PINV) / ((float)wn * PINV + EPS);
        l += (double)(a * a + c * c);
        if (wp | wn) nz += 1.0;
    }
    double lt = blk_reduce(l, sm);
    double nt = blk_reduce(nz, sm);
    if (threadIdx.x == 0) {
        bndL[j * BND_BLK + blockIdx.x] = lt;
        bndN[j * BND_BLK + blockIdx.x] = nt;
    }
}

// One block, 256 threads: 16 threads per job reduce accL/N + bndL/N
// (width-16 shfl); whole block reduces the 4 smooth sums.
__global__ __launch_bounds__(256) void final_kernel(
    const double* __restrict__ accL, const double* __restrict__ accN,
    const double* __restrict__ bndL, const double* __restrict__ bndN,
    const double* __restrict__ smP, float* __restrict__ out) {
    __shared__ double sj[16];
    __shared__ double sm[8];
    int tid = threadIdx.x;
    int j = tid >> 4, s = tid & 15;
    double l = 0.0, nz = 0.0;
    for (int i = s; i < TILES; i += 16) {
        l += accL[j * TILES + i];
        nz += accN[j * TILES + i];
    }
    for (int i = s; i < BND_BLK; i += 16) {
        l += bndL[j * BND_BLK + i];
        nz += bndN[j * BND_BLK + i];
    }
    #pragma unroll
    for (int o = 8; o > 0; o >>= 1) {
        l += __shfl_down(l, o, 16);
        nz += __shfl_down(nz, o, 16);
    }
    if (s == 0) sj[j] = l / nz;

    double c[4] = {0.0, 0.0, 0.0, 0.0};
    for (int i = tid; i < SM_BLK; i += 256) {
        #pragma unroll
        for (int k = 0; k < 4; ++k) c[k] += smP[i * 4 + k];
    }
    double s0 = blk_reduce(c[0], sm);
    double s1 = blk_reduce(c[1], sm);
    double s2 = blk_reduce(c[2], sm);
    double s3 = blk_reduce(c[3], sm);
    __syncthreads();
    if (tid == 0) {
        double loss = 0.0;
        for (int q = 0; q < 16; ++q) loss += sj[q];
        double ndx = (double)B * H * (W - 1);
        double ndy = (double)B * (H - 1) * W;
        double ndd = (double)B * (H - 1) * (W - 1);
        double smooth = (s0 / ndx + s1 / ndy + s2 / ndd + s3 / ndd) * 0.25;
        out[0] = (float)(loss + 0.001 * smooth);
    }
}

extern "C" void kernel_launch(void* const* d_in, const int* in_sizes, int n_in,
                              void* d_out, int out_size, void* d_ws, size_t ws_size,
                              hipStream_t stream) {
    const float* flow = (const float*)d_in[0];
    const float* ts   = (const float*)d_in[1];
    const int*   ys   = (const int*)d_in[2];
    const int*   xs   = (const int*)d_in[3];
    const int*   pol  = (const int*)d_in[4];
    float* out = (float*)d_out;

    char* ws = (char*)d_ws;
    double* accL = (double*)(ws + ACCL_OFF);
    double* accN = (double*)(ws + ACCN_OFF);
    double* bndL = (double*)(ws + BNDL_OFF);
    double* bndN = (double*)(ws + BNDN_OFF);
    double* smP  = (double*)(ws + SMP_OFF);
    unsigned* cursors = (unsigned*)(ws + CUR_OFF);
    unsigned long long* bndE = (unsigned long long*)(ws + BNDE_OFF);
    unsigned long long* items = (unsigned long long*)(ws + ITEMS_OFF);

    // Only cursors need zeroing (everything else is fully written by its
    // producer before being read).
    hipMemsetAsync(cursors, 0, (size_t)NBINS * 4, stream);
    scatter_smooth_kernel<<<SM_BLK + SC_BLOCKS, 256, 0, stream>>>(
        flow, ts, ys, xs, pol, items, cursors, smP);
    accum_kernel<<<NBINS, 256, 0, stream>>>(items, cursors, bndE, accL, accN);
    bound_kernel<<<dim3(BND_BLK, 16), 256, 0, stream>>>(bndE, bndL, bndN);
    final_kernel<<<1, 256, 0, stream>>>(accL, accN, bndL, bndN, smP, out);
}

// Round 8
// 145.682 us; speedup vs baseline: 7.9459x; 1.0299x over previous
//
#include <hip/hip_runtime.h>

// EventWarping: contrast-maximization loss for event-camera flow.
// flow [B,2,H,W] f32, ts [B,N,1] f32, ys/xs/pol [B,N] i32 -> scalar f32.
//
// Round 8: (a) accum tiles 48x64 -> 32x64: LDS 50->34KB, 3->4 blocks/CU;
// (b) accum/bound drop fixed-point rescale (eps folded: s/(w+PS*EPS)),
// f32 inner sums; (c) scatter loads 4 consecutive events per thread via
// int4/float4 (4 vector loads vs 16 scalar) and caches bin ids in regs.

constexpr int H = 480, W = 640, HW = H * W;
constexpr int B = 8, N = 131072;
constexpr float FLOW_SCALING = 640.0f;
constexpr float EPS = 1e-9f;

constexpr int TH = 32, TW = 64;            // tile size
constexpr int TILES_Y = H / TH;            // 15
constexpr int TILES_X = W / TW;            // 10
constexpr int TILES = TILES_Y * TILES_X;   // 150
constexpr int NBINS = B * 2 * TILES;       // 2400 (b, tref, tile)
constexpr int CAP = 3072;                  // slots per bin (mean ~873, ~74 sigma)

constexpr float PSCALE = 262144.0f;        // 2^18 fixed point
constexpr float EPS_S = PSCALE * EPS;      // eps in scaled domain (2.62e-4)

constexpr int BND_BLK = 56;                // bound grid.x
constexpr int SM_BLK = 512;                // smooth block count (fused, first)
constexpr int SC_BLOCKS = 1024;            // scatter block count (fused)

// Per-tile edge strip: seg0 ly=0 (65), seg1 ly=TH (65), seg2 lx=0,ly=1..TH-1
// (31), seg3 lx=TW,ly=1..TH-1 (31) => 192 entries x {pos,neg} u64.
constexpr int EDGE_PX = 2 * (TW + 1) + 2 * (TH - 1);   // 192

// Line-pixel index space per job: row-lines k*W+x (15*640), col-lines
// TILES_Y*W + m*H + y (10*480). Col entries with y%TH==0 owned by row-lines.
constexpr int BPX = TILES_Y * W + TILES_X * H;   // 14400

// Workspace layout:
constexpr size_t ACCL_OFF = 0;                                        // f64[16][150]
constexpr size_t ACCN_OFF = ACCL_OFF + (size_t)16 * TILES * 8;
constexpr size_t BNDL_OFF = ACCN_OFF + (size_t)16 * TILES * 8;
constexpr size_t BNDN_OFF = BNDL_OFF + (size_t)16 * BND_BLK * 8;
constexpr size_t SMP_OFF  = BNDN_OFF + (size_t)16 * BND_BLK * 8;
constexpr size_t CUR_OFF  = SMP_OFF + (size_t)SM_BLK * 4 * 8;
constexpr size_t BNDE_OFF = CUR_OFF + (size_t)NBINS * 4;
constexpr size_t BNDE_BYTES = (size_t)NBINS * EDGE_PX * 2 * 8;        // 7.37MB
constexpr size_t ITEMS_OFF = BNDE_OFF + BNDE_BYTES;                   // +59MB items

__device__ inline double blk_reduce(double v, double* sm) {
    __syncthreads();
    #pragma unroll
    for (int o = 32; o > 0; o >>= 1) v += __shfl_down(v, o, 64);
    int lane = threadIdx.x & 63;
    int wid  = threadIdx.x >> 6;
    if (lane == 0) sm[wid] = v;
    __syncthreads();
    double r = 0.0;
    if (threadIdx.x == 0) {
        int nw = (int)(blockDim.x >> 6);
        for (int w2 = 0; w2 < nw; ++w2) r += sm[w2];
    }
    return r;  // thread 0 only
}

// Local bin id (tref*TILES + tile) from the PACKED payload, so count and
// placement can never disagree.
__device__ inline int bin_from_payload(unsigned long long v) {
    int t = (int)(v & 1);
    int fyi = (int)((unsigned)(v >> 40) >> 12) - 512;
    int fxi = (int)(((unsigned)(v >> 16) & 0xFFFFFFu) >> 12) - 512;
    int cy = min(max(fyi, 0), H - 1);
    int cx = min(max(fxi, 0), W - 1);
    return t * TILES + (cy >> 5) * TILES_X + (cx >> 6);
}

__device__ inline float charb(float a, float b) {
    return sqrtf(a * a + b * b + 1e-6f);
}

// Fused: blocks [0, SM_BLK) smooth; [SM_BLK, +SC_BLOCKS) scatter.
// Scatter: batch = sc&7 (XCD pin; SM_BLK%8==0), 1024 events/block (4
// consecutive per thread, int4/float4 loads). Payload u64:
// [63:40] (wy+512)*4096 rn, [39:16] (wx+512)*4096 rn, [15:2] sw*16383 rn,
// [1] pol, [0] tref.
__global__ __launch_bounds__(256) void scatter_smooth_kernel(
    const float* __restrict__ flow, const float* __restrict__ ts,
    const int* __restrict__ ys, const int* __restrict__ xs,
    const int* __restrict__ pol,
    unsigned long long* __restrict__ items, unsigned* __restrict__ cursors,
    double* __restrict__ smP) {
    __shared__ unsigned scount[2 * TILES];
    __shared__ unsigned sbase[2 * TILES];
    __shared__ unsigned scur[2 * TILES];
    __shared__ double sm[8];
    int tid = threadIdx.x;

    if (blockIdx.x < SM_BLK) {
        // ---- smooth path ----
        int sb = blockIdx.x;
        double sdx = 0.0, sdy = 0.0, sdr = 0.0, sur = 0.0;
        int stride = SM_BLK * 256;
        for (int i = sb * 256 + tid; i < B * HW; i += stride) {
            int b = i / HW;
            int rem = i - b * HW;
            int y = rem / W;
            int x = rem - y * W;
            const float* fx = flow + (size_t)(b * 2 + 0) * HW;
            const float* fy = flow + (size_t)(b * 2 + 1) * HW;
            float f00 = fx[rem], g00 = fy[rem];
            bool xe = (x + 1) < W;
            bool ye = (y + 1) < H;
            if (xe) {
                float f01 = fx[rem + 1], g01 = fy[rem + 1];
                sdx += (double)charb(f00 - f01, g00 - g01);
                if (ye) {
                    float f10 = fx[rem + W], g10 = fy[rem + W];
                    float f11 = fx[rem + W + 1], g11 = fy[rem + W + 1];
                    sdy += (double)charb(f00 - f10, g00 - g10);
                    sdr += (double)charb(f00 - f11, g00 - g11);
                    sur += (double)charb(f10 - f01, g10 - g01);
                }
            } else if (ye) {
                float f10 = fx[rem + W], g10 = fy[rem + W];
                sdy += (double)charb(f00 - f10, g00 - g10);
            }
        }
        double tt;
        tt = blk_reduce(sdx, sm); if (tid == 0) smP[sb * 4 + 0] = tt;
        tt = blk_reduce(sdy, sm); if (tid == 0) smP[sb * 4 + 1] = tt;
        tt = blk_reduce(sdr, sm); if (tid == 0) smP[sb * 4 + 2] = tt;
        tt = blk_reduce(sur, sm); if (tid == 0) smP[sb * 4 + 3] = tt;
        return;
    }

    // ---- scatter path ----
    for (int i = tid; i < 2 * TILES; i += 256) { scount[i] = 0; scur[i] = 0; }
    __syncthreads();

    int sc = blockIdx.x - SM_BLK;
    int b = sc & 7;
    int chunk = sc >> 3;                  // 0..127
    int eb0 = b * N + chunk * 1024;       // multiple of 1024 -> 16B aligned
    const float* fb = flow + (size_t)b * 2 * HW;

    // 4 consecutive events per thread, vectorized loads.
    int4   yv = ((const int4*)(ys + eb0))[tid];
    int4   xv = ((const int4*)(xs + eb0))[tid];
    int4   pv = ((const int4*)(pol + eb0))[tid];
    float4 tv = ((const float4*)(ts + eb0))[tid];
    int y4[4] = {yv.x, yv.y, yv.z, yv.w};
    int x4[4] = {xv.x, xv.y, xv.z, xv.w};
    int p4[4] = {pv.x, pv.y, pv.z, pv.w};
    float t4[4] = {tv.x, tv.y, tv.z, tv.w};

    float fx4[4], fy4[4];
    #pragma unroll
    for (int k = 0; k < 4; ++k) {
        int flat = y4[k] * W + x4[k];
        fx4[k] = fb[flat];
        fy4[k] = fb[HW + flat];
    }

    unsigned long long pay[8];
    int bin8[8];
    #pragma unroll
    for (int k = 0; k < 4; ++k) {
        float t0 = t4[k];
        #pragma unroll
        for (int t = 0; t < 2; ++t) {
            float dt = (t == 0 ? 1.0f : 0.0f) - t0;
            float sw = (t == 0) ? t0 : 1.0f - t0;
            float wy = (float)y4[k] + dt * fy4[k] * FLOW_SCALING;
            float wx = (float)x4[k] + dt * fx4[k] * FLOW_SCALING;
            unsigned long long v = ~0ull;  // sentinel = invalid
            int binl = -1;
            if (wy >= -1.0f && wy < (float)H && wx >= -1.0f && wx < (float)W) {
                unsigned uy = __float2uint_rn((wy + 512.0f) * 4096.0f);
                unsigned ux = __float2uint_rn((wx + 512.0f) * 4096.0f);
                unsigned usw = __float2uint_rn(sw * 16383.0f);
                v = ((unsigned long long)uy << 40) |
                    ((unsigned long long)ux << 16) |
                    ((unsigned long long)usw << 2) |
                    ((unsigned long long)(p4[k] != 0) << 1) |
                    (unsigned long long)t;
                binl = bin_from_payload(v);
                atomicAdd(&scount[binl], 1u);
            }
            pay[k * 2 + t] = v;
            bin8[k * 2 + t] = binl;
        }
    }
    __syncthreads();
    for (int i = tid; i < 2 * TILES; i += 256) {
        unsigned c = scount[i];
        sbase[i] = c ? atomicAdd(&cursors[b * 2 * TILES + i], c) : 0u;
    }
    __syncthreads();
    #pragma unroll
    for (int i = 0; i < 8; ++i) {
        int binl = bin8[i];
        if (binl < 0) continue;
        unsigned idx = sbase[binl] + atomicAdd(&scur[binl], 1u);
        if (idx < (unsigned)CAP)
            items[(size_t)(b * 2 * TILES + binl) * CAP + idx] = pay[i];
    }
}

// One block per bin (b,t,tile). LDS tile 33x65 u64 per polarity field
// (0=pos, 1=neg), packing (w<<32 | s) at 2^18 fixed point. Interior pixels
// finalize in-LDS (f32, eps pre-scaled); edge pixels stored (no atomics)
// to the tile's private strip; bound gathers.
__global__ __launch_bounds__(256) void accum_kernel(
    const unsigned long long* __restrict__ items,
    const unsigned* __restrict__ cursors,
    unsigned long long* __restrict__ bndE,
    double* __restrict__ accL, double* __restrict__ accN) {
    constexpr int TPX = (TH + 1) * (TW + 1);      // 2145
    __shared__ unsigned long long sacc[2 * TPX];  // 34,320 B -> 4 blocks/CU
    __shared__ double sm[8];
    int tid = threadIdx.x;
    for (int i = tid; i < 2 * TPX; i += 256) sacc[i] = 0ull;
    __syncthreads();

    int bin = blockIdx.x;
    int b = bin / (2 * TILES);
    int loc = bin - b * (2 * TILES);
    int t = loc / TILES;
    int tile = loc - t * TILES;
    int y0 = (tile / TILES_X) * TH;
    int x0 = (tile % TILES_X) * TW;
    int cnt = (int)min(cursors[bin], (unsigned)CAP);
    const unsigned long long* bi = items + (size_t)bin * CAP;

    for (int i = tid; i < cnt; i += 256) {
        unsigned long long v = bi[i];
        unsigned uy = (unsigned)(v >> 40);
        unsigned ux = (unsigned)(v >> 16) & 0xFFFFFFu;
        float wy = (float)uy * (1.0f / 4096.0f) - 512.0f;
        float wx = (float)ux * (1.0f / 4096.0f) - 512.0f;
        int fyi = (int)(uy >> 12) - 512;
        int fxi = (int)(ux >> 12) - 512;
        float sw = (float)((unsigned)(v >> 2) & 0x3FFFu) * (1.0f / 16383.0f);
        int f = ((v >> 1) & 1) ? 0 : 1;  // pol=1 -> pos field
        #pragma unroll
        for (int dy = 0; dy < 2; ++dy) {
            int ry = fyi + dy, ly = ry - y0;
            if (ry < 0 || ry >= H || ly < 0 || ly > TH) continue;
            float wfy = 1.0f - fabsf(wy - (float)ry);
            #pragma unroll
            for (int dx = 0; dx < 2; ++dx) {
                int rx = fxi + dx, lx = rx - x0;
                if (rx < 0 || rx >= W || lx < 0 || lx > TW) continue;
                float wgt = wfy * (1.0f - fabsf(wx - (float)rx));
                int px = ly * (TW + 1) + lx;
                unsigned w18 = __float2uint_rn(wgt * PSCALE);
                unsigned s18 = __float2uint_rn(wgt * sw * PSCALE);
                atomicAdd(&sacc[f * TPX + px],
                          ((unsigned long long)w18 << 32) | s18);
            }
        }
    }
    __syncthreads();

    float lf = 0.0f;
    int nzi = 0;
    unsigned long long* eb = bndE + (size_t)bin * EDGE_PX * 2;
    for (int p = tid; p < TPX; p += 256) {
        int ly = p / (TW + 1), lx = p - ly * (TW + 1);
        unsigned long long vp = sacc[p];
        unsigned long long vn = sacc[TPX + p];
        // Edge classification (rows own corners).
        int slot = -1;
        if (ly == 0)           slot = lx;                        // seg0
        else if (ly == TH)     slot = (TW + 1) + lx;             // seg1
        else if (lx == 0)      slot = 2 * (TW + 1) + (ly - 1);   // seg2
        else if (lx == TW)     slot = 2 * (TW + 1) + (TH - 1) + (ly - 1);
        if (slot >= 0) {
            eb[(size_t)slot * 2]     = vp;   // unconditional: buffer unzeroed
            eb[(size_t)slot * 2 + 1] = vn;
        } else {
            // scaled domain: (s/PS)/(w/PS+EPS) == s/(w+PS*EPS)
            float a = (float)(unsigned)vp / ((float)(unsigned)(vp >> 32) + EPS_S);
            float c = (float)(unsigned)vn / ((float)(unsigned)(vn >> 32) + EPS_S);
            lf += a * a + c * c;
            nzi += ((vp | vn) >> 32) != 0ull;
        }
    }
    double lt = blk_reduce((double)lf, sm);
    double nt = blk_reduce((double)nzi, sm);
    if (tid == 0) {
        int j = b * 2 + t;
        accL[j * TILES + tile] = lt;   // distinct slot: NO atomics
        accN[j * TILES + tile] = nt;
    }
}

// Gather-reduce the line pixels. grid (BND_BLK, 16). Row-lines own corners;
// col entries with y%TH==0 contribute zero.
__global__ __launch_bounds__(256) void bound_kernel(
    const unsigned long long* __restrict__ bndE,
    double* __restrict__ bndL, double* __restrict__ bndN) {
    __shared__ double sm[8];
    int j = blockIdx.y;
    int b = j >> 1, t = j & 1;
    const unsigned long long* jb =
        bndE + (size_t)(b * 2 * TILES + t * TILES) * EDGE_PX * 2;

    float lf = 0.0f;
    int nzi = 0;
    for (int p = blockIdx.x * blockDim.x + threadIdx.x; p < BPX;
         p += gridDim.x * blockDim.x) {
        unsigned long long vp = 0ull, vn = 0ull;
        if (p < TILES_Y * W) {
            int k = p / W, x = p - k * W;
            int m = x >> 6, lx = x & 63;
            const unsigned long long* e;
            e = jb + ((size_t)(k * TILES_X + m) * EDGE_PX + lx) * 2;      // seg0
            vp += e[0]; vn += e[1];
            if (k > 0) {
                e = jb + ((size_t)((k - 1) * TILES_X + m) * EDGE_PX + (TW + 1) + lx) * 2;
                vp += e[0]; vn += e[1];
            }
            if (lx == 0 && m > 0) {
                e = jb + ((size_t)(k * TILES_X + m - 1) * EDGE_PX + TW) * 2;
                vp += e[0]; vn += e[1];
                if (k > 0) {
                    e = jb + ((size_t)((k - 1) * TILES_X + m - 1) * EDGE_PX + 2 * TW + 1) * 2;
                    vp += e[0]; vn += e[1];
                }
            }
        } else {
            int q = p - TILES_Y * W;
            int m = q / H, y = q - m * H;
            int r = y / TH, ly = y - r * TH;
            if (ly != 0) {
                const unsigned long long* e;
                e = jb + ((size_t)(r * TILES_X + m) * EDGE_PX + 2 * (TW + 1) + ly - 1) * 2;
                vp += e[0]; vn += e[1];
                if (m > 0) {
                    e = jb + ((size_t)(r * TILES_X + m - 1) * EDGE_PX
                              + 2 * (TW + 1) + (TH - 1) + ly - 1) * 2;
                    vp += e[0]; vn += e[1];
                }
            }
        }
        float a = (float)(unsigned)vp / ((float)(unsigned)(vp >> 32) + EPS_S);
        float c = (float)(unsigned)vn / ((float)(unsigned)(vn >> 32) + EPS_S);
        lf += a * a + c * c;
        nzi += ((vp | vn) >> 32) != 0ull;
    }
    double lt = blk_reduce((double)lf, sm);
    double nt = blk_reduce((double)nzi, sm);
    if (threadIdx.x == 0) {
        bndL[j * BND_BLK + blockIdx.x] = lt;
        bndN[j * BND_BLK + blockIdx.x] = nt;
    }
}

// One block, 256 threads: 16 threads per job reduce accL/N + bndL/N
// (width-16 shfl); whole block reduces the 4 smooth sums.
__global__ __launch_bounds__(256) void final_kernel(
    const double* __restrict__ accL, const double* __restrict__ accN,
    const double* __restrict__ bndL, const double* __restrict__ bndN,
    const double* __restrict__ smP, float* __restrict__ out) {
    __shared__ double sj[16];
    __shared__ double sm[8];
    int tid = threadIdx.x;
    int j = tid >> 4, s = tid & 15;
    double l = 0.0, nz = 0.0;
    for (int i = s; i < TILES; i += 16) {
        l += accL[j * TILES + i];
        nz += accN[j * TILES + i];
    }
    for (int i = s; i < BND_BLK; i += 16) {
        l += bndL[j * BND_BLK + i];
        nz += bndN[j * BND_BLK + i];
    }
    #pragma unroll
    for (int o = 8; o > 0; o >>= 1) {
        l += __shfl_down(l, o, 16);
        nz += __shfl_down(nz, o, 16);
    }
    if (s == 0) sj[j] = l / nz;

    double c[4] = {0.0, 0.0, 0.0, 0.0};
    for (int i = tid; i < SM_BLK; i += 256) {
        #pragma unroll
        for (int k = 0; k < 4; ++k) c[k] += smP[i * 4 + k];
    }
    double s0 = blk_reduce(c[0], sm);
    double s1 = blk_reduce(c[1], sm);
    double s2 = blk_reduce(c[2], sm);
    double s3 = blk_reduce(c[3], sm);
    __syncthreads();
    if (tid == 0) {
        double loss = 0.0;
        for (int q = 0; q < 16; ++q) loss += sj[q];
        double ndx = (double)B * H * (W - 1);
        double ndy = (double)B * (H - 1) * W;
        double ndd = (double)B * (H - 1) * (W - 1);
        double smooth = (s0 / ndx + s1 / ndy + s2 / ndd + s3 / ndd) * 0.25;
        out[0] = (float)(loss + 0.001 * smooth);
    }
}

extern "C" void kernel_launch(void* const* d_in, const int* in_sizes, int n_in,
                              void* d_out, int out_size, void* d_ws, size_t ws_size,
                              hipStream_t stream) {
    const float* flow = (const float*)d_in[0];
    const float* ts   = (const float*)d_in[1];
    const int*   ys   = (const int*)d_in[2];
    const int*   xs   = (const int*)d_in[3];
    const int*   pol  = (const int*)d_in[4];
    float* out = (float*)d_out;

    char* ws = (char*)d_ws;
    double* accL = (double*)(ws + ACCL_OFF);
    double* accN = (double*)(ws + ACCN_OFF);
    double* bndL = (double*)(ws + BNDL_OFF);
    double* bndN = (double*)(ws + BNDN_OFF);
    double* smP  = (double*)(ws + SMP_OFF);
    unsigned* cursors = (unsigned*)(ws + CUR_OFF);
    unsigned long long* bndE = (unsigned long long*)(ws + BNDE_OFF);
    unsigned long long* items = (unsigned long long*)(ws + ITEMS_OFF);

    // Only cursors need zeroing.
    hipMemsetAsync(cursors, 0, (size_t)NBINS * 4, stream);
    scatter_smooth_kernel<<<SM_BLK + SC_BLOCKS, 256, 0, stream>>>(
        flow, ts, ys, xs, pol, items, cursors, smP);
    accum_kernel<<<NBINS, 256, 0, stream>>>(items, cursors, bndE, accL, accN);
    bound_kernel<<<dim3(BND_BLK, 16), 256, 0, stream>>>(bndE, bndL, bndN);
    final_kernel<<<1, 256, 0, stream>>>(accL, accN, bndL, bndN, smP, out);
}